// Round 14
// baseline (450.626 us; speedup 1.0000x reference)
//
#include <hip/hip_runtime.h>
#include <hip/hip_bf16.h>
#include <math.h>

#define BB 32
#define SS 1024
#define DD 256
#define MM (BB*SS)   // 32768
#define LEPS 1e-5f

typedef __bf16 bf16x8 __attribute__((ext_vector_type(8)));
typedef __bf16 bf16x4 __attribute__((ext_vector_type(4)));
typedef float f32x4 __attribute__((ext_vector_type(4)));

// ---------------- weight cast+transpose: dst[l*dstride + (n+noff)*256 + k] = W[l][k][n]*scale
__global__ __launch_bounds__(256) void cast_wt(const float* __restrict__ W,
                                               __bf16* __restrict__ WT,
                                               int N, float scale, int dstride, int noff) {
    int n = blockIdx.x, l = blockIdx.z, k = threadIdx.x;
    WT[(size_t)dstride * l + (size_t)(n + noff) * 256 + k] =
        (__bf16)(W[(size_t)256 * N * l + (size_t)k * N + n] * scale);
}

// ---------------- combined k/q bias: dst[l][j] = j<64 ? bk*SC : bq
__global__ __launch_bounds__(128) void bias_combine(const float* __restrict__ bk,
                                                    const float* __restrict__ bq,
                                                    float* __restrict__ dst) {
    int l = blockIdx.x, j = threadIdx.x;
    dst[l * 128 + j] = (j < 64) ? bk[l * 64 + j] * 0.125f : bq[l * 64 + (j - 64)];
}

// ---------------- cast fp32 -> bf16, 8 elems/thread
__global__ __launch_bounds__(256) void cast_x(const float* __restrict__ x, __bf16* __restrict__ xb) {
    size_t i = ((size_t)blockIdx.x * 256 + threadIdx.x) * 8;
    float4 a = *(const float4*)(x + i);
    float4 b = *(const float4*)(x + i + 4);
    __bf16 o[8] __attribute__((aligned(16)));
    o[0] = (__bf16)a.x; o[1] = (__bf16)a.y; o[2] = (__bf16)a.z; o[3] = (__bf16)a.w;
    o[4] = (__bf16)b.x; o[5] = (__bf16)b.y; o[6] = (__bf16)b.z; o[7] = (__bf16)b.w;
    *(bf16x8*)(xb + i) = *(bf16x8*)o;
}

// ---------------- MFMA GEMM: C = A[M,256] @ WT[N,256]^T + bias, opt relu
// MODE: 0 = f32 out; 1 = bf16 out; 2 = kq split; 3 = batched vT producer (LDS-bounce stores)
template <int BN, int MODE>
__global__ __launch_bounds__(256) void gemm_mfma(const __bf16* __restrict__ A,
                                                 const __bf16* __restrict__ WT,
                                                 const float* __restrict__ bias,
                                                 float bscale, int relu,
                                                 void* __restrict__ Cv, void* __restrict__ Cv2,
                                                 int N) {
    constexpr int MR = (BN == 128) ? 4 : 2;
    constexpr int NC = (BN == 128) ? 4 : BN / 16;
    const int t = threadIdx.x;
    const int w = t >> 6, lane = t & 63;
    const int m0 = blockIdx.x * 128;
    const int n0 = blockIdx.y * BN;
    const size_t wt_z = (MODE == 3) ? (size_t)blockIdx.z * SS * 256 : 0;
    const size_t c_z  = (MODE == 3) ? (size_t)blockIdx.z * 256 * (size_t)N : 0;
    const int wr = (BN == 128) ? (w >> 1) * 64 : w * 32;
    const int wc = (BN == 128) ? (w & 1) * 64 : 0;
    __shared__ __align__(16) __bf16 smem[128 * 64 + BN * 64];
    __bf16 (*Al)[64] = (__bf16(*)[64])smem;
    __bf16 (*Wl)[64] = (__bf16(*)[64])(smem + 128 * 64);
    f32x4 acc[MR][NC] = {};

    for (int k0 = 0; k0 < 256; k0 += 64) {
        __syncthreads();
        {
            int r = t >> 1, half = t & 1;
            const __bf16* src = A + (size_t)(m0 + r) * 256 + k0 + half * 32;
            bf16x8 v0 = *(const bf16x8*)(src);
            bf16x8 v1 = *(const bf16x8*)(src + 8);
            bf16x8 v2 = *(const bf16x8*)(src + 16);
            bf16x8 v3 = *(const bf16x8*)(src + 24);
            int cb = half * 4;
            *(bf16x8*)&Al[r][((cb + 0) ^ (r & 7)) * 8] = v0;
            *(bf16x8*)&Al[r][((cb + 1) ^ (r & 7)) * 8] = v1;
            *(bf16x8*)&Al[r][((cb + 2) ^ (r & 7)) * 8] = v2;
            *(bf16x8*)&Al[r][((cb + 3) ^ (r & 7)) * 8] = v3;
        }
        if (BN == 128) {
            int r = t >> 1, half = t & 1;
            const __bf16* src = WT + wt_z + (size_t)(n0 + r) * 256 + k0 + half * 32;
            bf16x8 v0 = *(const bf16x8*)(src);
            bf16x8 v1 = *(const bf16x8*)(src + 8);
            bf16x8 v2 = *(const bf16x8*)(src + 16);
            bf16x8 v3 = *(const bf16x8*)(src + 24);
            int cb = half * 4;
            *(bf16x8*)&Wl[r][((cb + 0) ^ (r & 7)) * 8] = v0;
            *(bf16x8*)&Wl[r][((cb + 1) ^ (r & 7)) * 8] = v1;
            *(bf16x8*)&Wl[r][((cb + 2) ^ (r & 7)) * 8] = v2;
            *(bf16x8*)&Wl[r][((cb + 3) ^ (r & 7)) * 8] = v3;
        } else if (BN == 64) {
            int n = t >> 2, q = t & 3;
            const __bf16* src = WT + (size_t)(n0 + n) * 256 + k0 + q * 16;
            bf16x8 v0 = *(const bf16x8*)src;
            bf16x8 v1 = *(const bf16x8*)(src + 8);
            *(bf16x8*)&Wl[n][((q * 2 + 0) ^ (n & 7)) * 8] = v0;
            *(bf16x8*)&Wl[n][((q * 2 + 1) ^ (n & 7)) * 8] = v1;
        } else {
            if (t < 128) {
                int n = t >> 3, c = t & 7;
                bf16x8 v = *(const bf16x8*)(WT + (size_t)(n0 + n) * 256 + k0 + c * 8);
                *(bf16x8*)&Wl[n][(c ^ (n & 7)) * 8] = v;
            }
        }
        __syncthreads();
#pragma unroll
        for (int ks = 0; ks < 2; ks++) {
            int c = ks * 4 + (lane >> 4);
            bf16x8 af[MR];
#pragma unroll
            for (int mf = 0; mf < MR; mf++) {
                int i = wr + mf * 16 + (lane & 15);
                af[mf] = *(const bf16x8*)&Al[i][(c ^ (i & 7)) * 8];
            }
#pragma unroll
            for (int nf = 0; nf < NC; nf++) {
                int n = wc + nf * 16 + (lane & 15);
                bf16x8 bfr = *(const bf16x8*)&Wl[n][(c ^ (n & 7)) * 8];
#pragma unroll
                for (int mf = 0; mf < MR; mf++)
                    acc[mf][nf] = __builtin_amdgcn_mfma_f32_16x16x32_bf16(af[mf], bfr, acc[mf][nf], 0, 0, 0);
            }
        }
    }
    if (MODE == 3) {
        __syncthreads();
#pragma unroll
        for (int mf = 0; mf < MR; mf++) {
#pragma unroll
            for (int nf = 0; nf < NC; nf++) {
                int col = wc + nf * 16 + (lane & 15);
#pragma unroll
                for (int r = 0; r < 4; r++) {
                    int row = wr + mf * 16 + (lane >> 4) * 4 + r;
                    float v = acc[mf][nf][r] + bias[m0 + row];
                    smem[row * 128 + (((col >> 3) ^ (row & 15)) * 8) + (col & 7)] = (__bf16)v;
                }
            }
        }
        __syncthreads();
#pragma unroll
        for (int p = 0; p < 2; p++) {
            int row = p * 64 + (t >> 2);
            int cq = (t & 3) * 4;
            __bf16* dst = (__bf16*)Cv + c_z + (size_t)(m0 + row) * N + n0 + (t & 3) * 32;
#pragma unroll
            for (int u = 0; u < 4; u++) {
                int ch = (cq + u) ^ (row & 15);
                *(bf16x8*)(dst + u * 8) = *(const bf16x8*)&smem[row * 128 + ch * 8];
            }
        }
        return;
    }
#pragma unroll
    for (int mf = 0; mf < MR; mf++) {
#pragma unroll
        for (int nf = 0; nf < NC; nf++) {
            int col = n0 + wc + nf * 16 + (lane & 15);
            float bcol = bias[col] * bscale;
#pragma unroll
            for (int r = 0; r < 4; r++) {
                int row = m0 + wr + mf * 16 + (lane >> 4) * 4 + r;
                float v = acc[mf][nf][r] + bcol;
                if (relu) v = fmaxf(v, 0.f);
                if (MODE == 2) {
                    if (col < 64) ((__bf16*)Cv)[(size_t)row * 64 + col] = (__bf16)v;
                    else ((__bf16*)Cv2)[(size_t)row * 64 + (col - 64)] = (__bf16)v;
                } else if (MODE == 1) {
                    ((__bf16*)Cv)[(size_t)row * N + col] = (__bf16)v;
                } else {
                    ((float*)Cv)[(size_t)row * N + col] = v;
                }
            }
        }
    }
}

// ---------------- bias gemv (bf16 x): out[r] = x[r,:] . Wb[:,0] + bb[0]
__global__ __launch_bounds__(256) void bias_gemv(const __bf16* __restrict__ X,
                                                 const float* __restrict__ Wb,
                                                 const float* __restrict__ bb,
                                                 float* __restrict__ out) {
    int wave = threadIdx.x >> 6, lane = threadIdx.x & 63;
    size_t row = (size_t)blockIdx.x * 4 + wave;
    bf16x4 xv = *(const bf16x4*)(X + row * 256 + lane * 4);
    float4 wv = *(const float4*)(Wb + lane * 4);
    float p = (float)xv[0] * wv.x + (float)xv[1] * wv.y + (float)xv[2] * wv.z + (float)xv[3] * wv.w;
    for (int off = 32; off; off >>= 1) p += __shfl_down(p, off, 64);
    if (lane == 0) out[row] = p + bb[0];
}

// ---------------- MFMA fused attention + LN1 (8 waves, j-tile 64, 16x16 MFMA)
// v6: R11 main loop + K/bias in registers (no Kl/bsh LDS). T14 async-stage + setprio.
__global__ __launch_bounds__(512, 4) void attn_mfma(const __bf16* __restrict__ kb,
                                                    const __bf16* __restrict__ qb,
                                                    const __bf16* __restrict__ vT,
                                                    const float* __restrict__ biasb,
                                                    const __bf16* __restrict__ xinb,
                                                    const float* __restrict__ gamma,
                                                    const float* __restrict__ beta,
                                                    __bf16* __restrict__ outb) {
    int h = blockIdx.x;
    int blow = h & 7, rest = h >> 3;
    int ib = rest & 15;
    int b = blow + (rest >> 4) * 8;
    const int i0 = ib * 64;
    const int t = threadIdx.x;
    const int w = t >> 6, lane = t & 63;
    const int iq = w >> 1;
    const int dhalf = w & 1;

    __shared__ __align__(16) __bf16 Ql[64][64];
    __shared__ __align__(16) __bf16 Vl[256][64];
    __shared__ __align__(16) __bf16 Sl[64][64];
    __shared__ float rowred[2][64][2];

    // K fragments in registers (loop-invariant): row iq*16 + (lane&15), k = ks*32 + (lane>>4)*8
    bf16x8 kf[2];
    {
        const __bf16* kr = kb + ((size_t)(b * SS + i0 + iq * 16 + (lane & 15))) * 64 + (lane >> 4) * 8;
        kf[0] = *(const bf16x8*)(kr);
        kf[1] = *(const bf16x8*)(kr + 32);
    }
    // bias in registers: rows iq*16 + (lane>>4)*4 + r
    float4 biasr = *(const float4*)(biasb + (size_t)b * SS + i0 + iq * 16 + (lane >> 4) * 4);

    const int qj = t >> 3, qc = t & 7;
    const __bf16* qsrc_base = qb + ((size_t)(b * SS + qj)) * 64 + qc * 8;
    const int vd = t >> 1, vjh = t & 1;
    const __bf16* vsrc_base = vT + ((size_t)b * 256 + vd) * SS + vjh * 32;

    {   // prologue: stage Q/V for j0=0
        bf16x8 qv = *(const bf16x8*)(qsrc_base);
        *(bf16x8*)&Ql[qj][(qc ^ (qj & 7)) * 8] = qv;
#pragma unroll
        for (int u = 0; u < 4; u++) {
            bf16x8 v = *(const bf16x8*)(vsrc_base + u * 8);
            *(bf16x8*)&Vl[vd][((vjh * 4 + u) ^ (vd & 7)) * 8] = v;
        }
    }
    __syncthreads();

    f32x4 acc[8] = {};

    for (int j0 = 0; j0 < SS; j0 += 64) {
        const bool has_next = (j0 + 64) < SS;
        bf16x8 qn;
        bf16x8 vn0, vn1, vn2, vn3;
        if (has_next) {
            qn = *(const bf16x8*)(qsrc_base + (size_t)(j0 + 64) * 64);
            const __bf16* vs = vsrc_base + j0 + 64;
            vn0 = *(const bf16x8*)(vs);
            vn1 = *(const bf16x8*)(vs + 8);
            vn2 = *(const bf16x8*)(vs + 16);
            vn3 = *(const bf16x8*)(vs + 24);
        }
        // ---- S phase (K from regs, Q from LDS)
#pragma unroll
        for (int jj = 0; jj < 2; jj++) {
            int jq = (w & 1) * 2 + jj;
            f32x4 sacc = {0.f, 0.f, 0.f, 0.f};
            __builtin_amdgcn_s_setprio(1);
#pragma unroll
            for (int ks = 0; ks < 2; ks++) {
                int j = jq * 16 + (lane & 15);
                int ck = ks * 4 + (lane >> 4);
                bf16x8 bq = *(const bf16x8*)&Ql[j][(ck ^ (j & 7)) * 8];
                sacc = __builtin_amdgcn_mfma_f32_16x16x32_bf16(kf[ks], bq, sacc, 0, 0, 0);
            }
            __builtin_amdgcn_s_setprio(0);
            int jcol = jq * 16 + (lane & 15);
#pragma unroll
            for (int r = 0; r < 4; r++) {
                int irow = iq * 16 + (lane >> 4) * 4 + r;
                float x = sacc[r] + biasr[r];
                float sg = 1.f / (1.f + __expf(-x));
                Sl[irow][(((jcol >> 3) ^ (irow & 7)) * 8) + (jcol & 7)] = (__bf16)sg;
            }
        }
        __syncthreads();
        // ---- PV phase
        bf16x8 am[2];
#pragma unroll
        for (int m = 0; m < 2; m++) {
            int i = iq * 16 + (lane & 15);
            int cj = m * 4 + (lane >> 4);
            am[m] = *(const bf16x8*)&Sl[i][(cj ^ (i & 7)) * 8];
        }
        __builtin_amdgcn_s_setprio(1);
#pragma unroll
        for (int dq = 0; dq < 8; dq++) {
            int d = dhalf * 128 + dq * 16 + (lane & 15);
#pragma unroll
            for (int m = 0; m < 2; m++) {
                int cj = m * 4 + (lane >> 4);
                bf16x8 bv = *(const bf16x8*)&Vl[d][(cj ^ (d & 7)) * 8];
                acc[dq] = __builtin_amdgcn_mfma_f32_16x16x32_bf16(am[m], bv, acc[dq], 0, 0, 0);
            }
        }
        __builtin_amdgcn_s_setprio(0);
        __syncthreads();
        if (has_next) {
            *(bf16x8*)&Ql[qj][(qc ^ (qj & 7)) * 8] = qn;
            *(bf16x8*)&Vl[vd][((vjh * 4 + 0) ^ (vd & 7)) * 8] = vn0;
            *(bf16x8*)&Vl[vd][((vjh * 4 + 1) ^ (vd & 7)) * 8] = vn1;
            *(bf16x8*)&Vl[vd][((vjh * 4 + 2) ^ (vd & 7)) * 8] = vn2;
            *(bf16x8*)&Vl[vd][((vjh * 4 + 3) ^ (vd & 7)) * 8] = vn3;
            __syncthreads();
        }
    }

    // ---- fused LN1 epilogue (bf16 residual)
#pragma unroll
    for (int r = 0; r < 4; r++) {
        int il = iq * 16 + (lane >> 4) * 4 + r;
        size_t rowoff = ((size_t)(b * SS + i0 + il)) * 256 + dhalf * 128 + (lane & 15);
#pragma unroll
        for (int dq = 0; dq < 8; dq++)
            acc[dq][r] += (float)xinb[rowoff + dq * 16];
    }
    float sr[4], qr[4];
#pragma unroll
    for (int r = 0; r < 4; r++) {
        float s = 0.f, q = 0.f;
#pragma unroll
        for (int dq = 0; dq < 8; dq++) {
            float v = acc[dq][r];
            s += v; q += v * v;
        }
#pragma unroll
        for (int mask = 8; mask; mask >>= 1) {
            s += __shfl_xor(s, mask, 64);
            q += __shfl_xor(q, mask, 64);
        }
        sr[r] = s; qr[r] = q;
    }
    if ((lane & 15) == 0) {
#pragma unroll
        for (int r = 0; r < 4; r++) {
            int il = iq * 16 + (lane >> 4) * 4 + r;
            rowred[dhalf][il][0] = sr[r];
            rowred[dhalf][il][1] = qr[r];
        }
    }
    __syncthreads();
    float gv[8], bv2[8];
#pragma unroll
    for (int dq = 0; dq < 8; dq++) {
        int d = dhalf * 128 + dq * 16 + (lane & 15);
        gv[dq] = gamma[d];
        bv2[dq] = beta[d];
    }
#pragma unroll
    for (int r = 0; r < 4; r++) {
        int il = iq * 16 + (lane >> 4) * 4 + r;
        float st = rowred[0][il][0] + rowred[1][il][0];
        float qt = rowred[0][il][1] + rowred[1][il][1];
        float mean = st * (1.f / 256.f);
        float var = qt * (1.f / 256.f) - mean * mean;
        float inv = 1.f / sqrtf(var + LEPS);
        size_t rowoff = ((size_t)(b * SS + i0 + il)) * 256 + dhalf * 128 + (lane & 15);
#pragma unroll
        for (int dq = 0; dq < 8; dq++) {
            float o = (acc[dq][r] - mean) * inv * gv[dq] + bv2[dq];
            outb[rowoff + dq * 16] = (__bf16)o;
        }
    }
}

// ---------------- ff GEMM (BM=64, BN=256, 8 waves, grid 512) + fused LN2 (no affine)
__global__ __launch_bounds__(512) void gemm_ff_ln2(const __bf16* __restrict__ A,
                                                   const __bf16* __restrict__ WT,
                                                   const float* __restrict__ bias,
                                                   const __bf16* __restrict__ resid,
                                                   __bf16* __restrict__ outb) {
    const int t = threadIdx.x;
    const int w = t >> 6, lane = t & 63;
    const int m0 = blockIdx.x * 64;
    const int wr = (w >> 2) * 32, wc = (w & 3) * 64;
    __shared__ __align__(16) __bf16 Al[64][64];
    __shared__ __align__(16) __bf16 Wl[256][64];
    __shared__ float rowred[4][64][2];
    f32x4 acc[2][4] = {};

    for (int k0 = 0; k0 < 256; k0 += 64) {
        __syncthreads();
        {
            int r = t >> 3, c = t & 7;
            bf16x8 v = *(const bf16x8*)(A + (size_t)(m0 + r) * 256 + k0 + c * 8);
            *(bf16x8*)&Al[r][(c ^ (r & 7)) * 8] = v;
        }
        {
            int n = t >> 1, c0 = (t & 1) * 4;
            const __bf16* src = WT + (size_t)n * 256 + k0 + c0 * 8;
#pragma unroll
            for (int u = 0; u < 4; u++) {
                bf16x8 v = *(const bf16x8*)(src + u * 8);
                *(bf16x8*)&Wl[n][((c0 + u) ^ (n & 7)) * 8] = v;
            }
        }
        __syncthreads();
#pragma unroll
        for (int ks = 0; ks < 2; ks++) {
            int c = ks * 4 + (lane >> 4);
            bf16x8 af[2];
#pragma unroll
            for (int mf = 0; mf < 2; mf++) {
                int i = wr + mf * 16 + (lane & 15);
                af[mf] = *(const bf16x8*)&Al[i][(c ^ (i & 7)) * 8];
            }
#pragma unroll
            for (int nf = 0; nf < 4; nf++) {
                int n = wc + nf * 16 + (lane & 15);
                bf16x8 bfr = *(const bf16x8*)&Wl[n][(c ^ (n & 7)) * 8];
#pragma unroll
                for (int mf = 0; mf < 2; mf++)
                    acc[mf][nf] = __builtin_amdgcn_mfma_f32_16x16x32_bf16(af[mf], bfr, acc[mf][nf], 0, 0, 0);
            }
        }
    }
    float colb[4];
#pragma unroll
    for (int nf = 0; nf < 4; nf++) colb[nf] = bias[wc + nf * 16 + (lane & 15)];
#pragma unroll
    for (int mf = 0; mf < 2; mf++) {
#pragma unroll
        for (int r = 0; r < 4; r++) {
            int rl = wr + mf * 16 + (lane >> 4) * 4 + r;
            const __bf16* rrow = resid + (size_t)(m0 + rl) * 256 + wc + (lane & 15);
            float s = 0.f, q = 0.f;
#pragma unroll
            for (int nf = 0; nf < 4; nf++) {
                float v = fmaxf(acc[mf][nf][r] + colb[nf], 0.f) + (float)rrow[nf * 16];
                acc[mf][nf][r] = v;
                s += v; q += v * v;
            }
#pragma unroll
            for (int msk = 1; msk <= 8; msk <<= 1) {
                s += __shfl_xor(s, msk, 64);
                q += __shfl_xor(q, msk, 64);
            }
            if ((lane & 15) == 0) {
                rowred[w & 3][rl][0] = s;
                rowred[w & 3][rl][1] = q;
            }
        }
    }
    __syncthreads();
#pragma unroll
    for (int mf = 0; mf < 2; mf++) {
#pragma unroll
        for (int r = 0; r < 4; r++) {
            int rl = wr + mf * 16 + (lane >> 4) * 4 + r;
            float s = rowred[0][rl][0] + rowred[1][rl][0] + rowred[2][rl][0] + rowred[3][rl][0];
            float q = rowred[0][rl][1] + rowred[1][rl][1] + rowred[2][rl][1] + rowred[3][rl][1];
            float mean = s * (1.f / 256.f);
            float var = q * (1.f / 256.f) - mean * mean;
            float inv = 1.f / sqrtf(var + LEPS);
            size_t base = (size_t)(m0 + rl) * 256 + wc + (lane & 15);
#pragma unroll
            for (int nf = 0; nf < 4; nf++) {
                float o = (acc[mf][nf][r] - mean) * inv;
                outb[base + nf * 16] = (__bf16)o;
            }
        }
    }
}

// ---------------- pooling P1: per-(b,h) softmax -> normalized weights
__global__ __launch_bounds__(256) void pool_softmax(const float* __restrict__ pk,
                                                    const float* __restrict__ queries,
                                                    float* __restrict__ wout) {
    const int b = blockIdx.x, h = blockIdx.y;
    const int t = threadIdx.x;
    const int wv = t >> 6, lane = t & 63;
    __shared__ float qv[16];
    __shared__ float redm[4], reds[4];
    if (t < 16) qv[t] = queries[h * 16 + t];
    __syncthreads();
    float sc[4];
#pragma unroll
    for (int c = 0; c < 4; c++) {
        int s = c * 256 + t;
        const float* p = pk + ((size_t)b * SS + s) * 16;
        float4 a0 = *(const float4*)p;
        float4 a1 = *(const float4*)(p + 4);
        float4 a2 = *(const float4*)(p + 8);
        float4 a3 = *(const float4*)(p + 12);
        sc[c] = a0.x * qv[0] + a0.y * qv[1] + a0.z * qv[2] + a0.w * qv[3]
              + a1.x * qv[4] + a1.y * qv[5] + a1.z * qv[6] + a1.w * qv[7]
              + a2.x * qv[8] + a2.y * qv[9] + a2.z * qv[10] + a2.w * qv[11]
              + a3.x * qv[12] + a3.y * qv[13] + a3.z * qv[14] + a3.w * qv[15];
    }
    float m = fmaxf(fmaxf(sc[0], sc[1]), fmaxf(sc[2], sc[3]));
    for (int off = 32; off; off >>= 1) m = fmaxf(m, __shfl_xor(m, off, 64));
    if (lane == 0) redm[wv] = m;
    __syncthreads();
    m = fmaxf(fmaxf(redm[0], redm[1]), fmaxf(redm[2], redm[3]));
    float e[4];
    float sum = 0.f;
#pragma unroll
    for (int c = 0; c < 4; c++) { e[c] = expf(sc[c] - m); sum += e[c]; }
    for (int off = 32; off; off >>= 1) sum += __shfl_xor(sum, off, 64);
    if (lane == 0) reds[wv] = sum;
    __syncthreads();
    float inv = 1.f / (reds[0] + reds[1] + reds[2] + reds[3]);
#pragma unroll
    for (int c = 0; c < 4; c++)
        wout[((size_t)(b * 4 + h)) * SS + c * 256 + t] = e[c] * inv;
}

// ---------------- pooling P2: partial weighted sums over s-chunks of 64
__global__ __launch_bounds__(256) void pool_wsum(const float* __restrict__ wgt,
                                                 const float* __restrict__ pv,
                                                 float* __restrict__ partial) {
    const int b = blockIdx.x, c = blockIdx.y;
    const int h = threadIdx.x >> 6, d = threadIdx.x & 63;
    const float* wrow = wgt + ((size_t)(b * 4 + h)) * SS + c * 64;
    const float* pvb = pv + ((size_t)(b * SS + c * 64)) * 64 + d;
    float a = 0.f;
#pragma unroll 8
    for (int s = 0; s < 64; s++) a += wrow[s] * pvb[(size_t)s * 64];
    partial[((size_t)b * 16 + c) * 256 + threadIdx.x] = a;
}

// ---------------- pooling P3: reduce partials + final linear
__global__ __launch_bounds__(256) void pool_final(const float* __restrict__ partial,
                                                  const float* __restrict__ W1,
                                                  const float* __restrict__ b1,
                                                  float* __restrict__ out) {
    const int b = blockIdx.x, t = threadIdx.x;
    __shared__ float r0[256], r1[256];
    float a = 0.f;
#pragma unroll
    for (int c = 0; c < 16; c++) a += partial[((size_t)b * 16 + c) * 256 + t];
    r0[t] = a * W1[t * 2 + 0];
    r1[t] = a * W1[t * 2 + 1];
    __syncthreads();
    for (int off = 128; off > 0; off >>= 1) {
        if (t < off) { r0[t] += r0[t + off]; r1[t] += r1[t + off]; }
        __syncthreads();
    }
    if (t == 0) {
        out[b * 2 + 0] = r0[0] + b1[0];
        out[b * 2 + 1] = r1[0] + b1[1];
    }
}

extern "C" void kernel_launch(void* const* d_in, const int* in_sizes, int n_in,
                              void* d_out, int out_size, void* d_ws, size_t ws_size,
                              hipStream_t stream) {
    const float* input = (const float*)d_in[0];
    const float* eWk = (const float*)d_in[3];
    const float* ebk = (const float*)d_in[4];
    const float* eWq = (const float*)d_in[5];
    const float* ebq = (const float*)d_in[6];
    const float* eWv = (const float*)d_in[7];
    const float* ebv = (const float*)d_in[8];
    const float* eWb = (const float*)d_in[9];
    const float* ebb = (const float*)d_in[10];
    const float* eWff = (const float*)d_in[11];
    const float* ebff = (const float*)d_in[12];
    const float* eg1 = (const float*)d_in[13];
    const float* ebe1 = (const float*)d_in[14];
    const float* pWk = (const float*)d_in[15];
    const float* pbk = (const float*)d_in[16];
    const float* pWv = (const float*)d_in[17];
    const float* pbv = (const float*)d_in[18];
    const float* qrs = (const float*)d_in[19];
    const float* W1 = (const float*)d_in[20];
    const float* b1 = (const float*)d_in[21];
    float* out = (float*)d_out;

    // ---- workspace layout (bf16-only inter-kernel dataflow)
    float* ws = (float*)d_ws;
    float* xbuf = ws;                               // (reserved)
    __bf16* xbf = (__bf16*)(xbuf + (size_t)MM * DD);      // MM*256 bf16 — THE x
    float* tmp2 = (float*)(xbf + (size_t)MM * DD);        // tail scratch
    float* r3 = tmp2 + (size_t)MM * DD;
    __bf16* tmp2bf = (__bf16*)r3;                   //   LN1 bf16 (attn epilogue)
    __bf16* vTb = tmp2bf + (size_t)MM * DD;         //   vT [B][256][1024]
    float* r4 = r3 + (size_t)MM * DD;
    __bf16* kbf = (__bf16*)r4;                      //   k bf16
    __bf16* qbf = kbf + (size_t)MM * 64;            //   q bf16
    float* bbuf = r4 + (size_t)MM * (DD / 2);       // MM f32
    __bf16* wbf = (__bf16*)(bbuf + MM);             // weights bf16

    __bf16* WkqT = wbf;                     // [4][128][256]
    __bf16* WvT = WkqT + 4 * 128 * 256;     // [4][256][256]
    __bf16* WffT = WvT + 4 * 256 * 256;     // [4][256][256]
    __bf16* pWkT = WffT + 4 * 256 * 256;    // [16][256], pre-scaled
    __bf16* pWvT = pWkT + 16 * 256;         // [64][256]
    float* biasc = (float*)(pWvT + 64 * 256);  // [4][128]

    // tail-phase buffers inside tmp2 region
    float* pkbuf = tmp2;                        // MM*16
    float* pvbuf = tmp2 + (size_t)MM * 16;      // MM*64
    float* wgtbuf = tmp2 + (size_t)MM * 80;     // 32*4*1024
    float* partial = wgtbuf + (size_t)BB * 4 * SS;  // 32*16*256

    const float SC = 0.125f;  // 1/sqrt(64)

    cast_wt<<<dim3(64, 1, 4), 256, 0, stream>>>(eWk, WkqT, 64, SC, 128 * 256, 0);
    cast_wt<<<dim3(64, 1, 4), 256, 0, stream>>>(eWq, WkqT, 64, 1.f, 128 * 256, 64);
    cast_wt<<<dim3(256, 1, 4), 256, 0, stream>>>(eWv, WvT, 256, 1.f, 256 * 256, 0);
    cast_wt<<<dim3(256, 1, 4), 256, 0, stream>>>(eWff, WffT, 256, 1.f, 256 * 256, 0);
    cast_wt<<<dim3(16, 1, 1), 256, 0, stream>>>(pWk, pWkT, 16, SC, 16 * 256, 0);
    cast_wt<<<dim3(64, 1, 1), 256, 0, stream>>>(pWv, pWvT, 64, 1.f, 64 * 256, 0);
    bias_combine<<<4, 128, 0, stream>>>(ebk, ebq, biasc);
    cast_x<<<MM * DD / (256 * 8), 256, 0, stream>>>(input, xbf);

    for (int l = 0; l < 4; l++) {
        gemm_mfma<128, 2><<<dim3(MM / 128, 1), 256, 0, stream>>>(
            xbf, WkqT + (size_t)l * 128 * 256, biasc + l * 128, 1.f, 0, kbf, qbf, 64);
        gemm_mfma<128, 3><<<dim3(2, SS / 128, BB), 256, 0, stream>>>(
            WvT + (size_t)l * 256 * 256, xbf, ebv + l * DD, 1.f, 0, vTb, nullptr, SS);
        bias_gemv<<<MM / 4, 256, 0, stream>>>(xbf, eWb + (size_t)l * DD, ebb + l, bbuf);
        attn_mfma<<<dim3(512, 1), 512, 0, stream>>>(kbf, qbf, vTb, bbuf, xbf,
                                                    eg1 + l * DD, ebe1 + l * DD, tmp2bf);
        gemm_ff_ln2<<<dim3(MM / 64, 1), 512, 0, stream>>>(
            tmp2bf, WffT + (size_t)l * 256 * 256, ebff + l * DD, tmp2bf, xbf);
    }
    gemm_mfma<16, 0><<<dim3(MM / 128, 1), 256, 0, stream>>>(xbf, pWkT, pbk, SC, 0, pkbuf, nullptr, 16);
    gemm_mfma<64, 0><<<dim3(MM / 128, 1), 256, 0, stream>>>(xbf, pWvT, pbv, 1.f, 0, pvbuf, nullptr, 64);
    pool_softmax<<<dim3(BB, 4), 256, 0, stream>>>(pkbuf, qrs, wgtbuf);
    pool_wsum<<<dim3(BB, 16), 256, 0, stream>>>(wgtbuf, pvbuf, partial);
    pool_final<<<BB, 256, 0, stream>>>(partial, W1, b1, out);
}

// Round 15
// 440.100 us; speedup vs baseline: 1.0239x; 1.0239x over previous
//
#include <hip/hip_runtime.h>
#include <hip/hip_bf16.h>
#include <math.h>

#define BB 32
#define SS 1024
#define DD 256
#define MM (BB*SS)   // 32768
#define LEPS 1e-5f

typedef __bf16 bf16x8 __attribute__((ext_vector_type(8)));
typedef __bf16 bf16x4 __attribute__((ext_vector_type(4)));
typedef float f32x4 __attribute__((ext_vector_type(4)));

// ---------------- weight cast+transpose: dst[l*dstride + (n+noff)*256 + k] = W[l][k][n]*scale
__global__ __launch_bounds__(256) void cast_wt(const float* __restrict__ W,
                                               __bf16* __restrict__ WT,
                                               int N, float scale, int dstride, int noff) {
    int n = blockIdx.x, l = blockIdx.z, k = threadIdx.x;
    WT[(size_t)dstride * l + (size_t)(n + noff) * 256 + k] =
        (__bf16)(W[(size_t)256 * N * l + (size_t)k * N + n] * scale);
}

// ---------------- combined k/q bias: dst[l][j] = j<64 ? bk*SC : bq
__global__ __launch_bounds__(128) void bias_combine(const float* __restrict__ bk,
                                                    const float* __restrict__ bq,
                                                    float* __restrict__ dst) {
    int l = blockIdx.x, j = threadIdx.x;
    dst[l * 128 + j] = (j < 64) ? bk[l * 64 + j] * 0.125f : bq[l * 64 + (j - 64)];
}

// ---------------- cast fp32 -> bf16, 8 elems/thread
__global__ __launch_bounds__(256) void cast_x(const float* __restrict__ x, __bf16* __restrict__ xb) {
    size_t i = ((size_t)blockIdx.x * 256 + threadIdx.x) * 8;
    float4 a = *(const float4*)(x + i);
    float4 b = *(const float4*)(x + i + 4);
    __bf16 o[8] __attribute__((aligned(16)));
    o[0] = (__bf16)a.x; o[1] = (__bf16)a.y; o[2] = (__bf16)a.z; o[3] = (__bf16)a.w;
    o[4] = (__bf16)b.x; o[5] = (__bf16)b.y; o[6] = (__bf16)b.z; o[7] = (__bf16)b.w;
    *(bf16x8*)(xb + i) = *(bf16x8*)o;
}

// ---------------- MFMA GEMM: C = A[M,256] @ WT[N,256]^T + bias, opt relu
// MODE: 0 = f32 out; 1 = bf16 out; 2 = kq split; 3 = batched vT producer (LDS-bounce stores)
template <int BN, int MODE>
__global__ __launch_bounds__(256) void gemm_mfma(const __bf16* __restrict__ A,
                                                 const __bf16* __restrict__ WT,
                                                 const float* __restrict__ bias,
                                                 float bscale, int relu,
                                                 void* __restrict__ Cv, void* __restrict__ Cv2,
                                                 int N) {
    constexpr int MR = (BN == 128) ? 4 : 2;
    constexpr int NC = (BN == 128) ? 4 : BN / 16;
    const int t = threadIdx.x;
    const int w = t >> 6, lane = t & 63;
    const int m0 = blockIdx.x * 128;
    const int n0 = blockIdx.y * BN;
    const size_t wt_z = (MODE == 3) ? (size_t)blockIdx.z * SS * 256 : 0;
    const size_t c_z  = (MODE == 3) ? (size_t)blockIdx.z * 256 * (size_t)N : 0;
    const int wr = (BN == 128) ? (w >> 1) * 64 : w * 32;
    const int wc = (BN == 128) ? (w & 1) * 64 : 0;
    __shared__ __align__(16) __bf16 smem[128 * 64 + BN * 64];
    __bf16 (*Al)[64] = (__bf16(*)[64])smem;
    __bf16 (*Wl)[64] = (__bf16(*)[64])(smem + 128 * 64);
    f32x4 acc[MR][NC] = {};

    for (int k0 = 0; k0 < 256; k0 += 64) {
        __syncthreads();
        {
            int r = t >> 1, half = t & 1;
            const __bf16* src = A + (size_t)(m0 + r) * 256 + k0 + half * 32;
            bf16x8 v0 = *(const bf16x8*)(src);
            bf16x8 v1 = *(const bf16x8*)(src + 8);
            bf16x8 v2 = *(const bf16x8*)(src + 16);
            bf16x8 v3 = *(const bf16x8*)(src + 24);
            int cb = half * 4;
            *(bf16x8*)&Al[r][((cb + 0) ^ (r & 7)) * 8] = v0;
            *(bf16x8*)&Al[r][((cb + 1) ^ (r & 7)) * 8] = v1;
            *(bf16x8*)&Al[r][((cb + 2) ^ (r & 7)) * 8] = v2;
            *(bf16x8*)&Al[r][((cb + 3) ^ (r & 7)) * 8] = v3;
        }
        if (BN == 128) {
            int r = t >> 1, half = t & 1;
            const __bf16* src = WT + wt_z + (size_t)(n0 + r) * 256 + k0 + half * 32;
            bf16x8 v0 = *(const bf16x8*)(src);
            bf16x8 v1 = *(const bf16x8*)(src + 8);
            bf16x8 v2 = *(const bf16x8*)(src + 16);
            bf16x8 v3 = *(const bf16x8*)(src + 24);
            int cb = half * 4;
            *(bf16x8*)&Wl[r][((cb + 0) ^ (r & 7)) * 8] = v0;
            *(bf16x8*)&Wl[r][((cb + 1) ^ (r & 7)) * 8] = v1;
            *(bf16x8*)&Wl[r][((cb + 2) ^ (r & 7)) * 8] = v2;
            *(bf16x8*)&Wl[r][((cb + 3) ^ (r & 7)) * 8] = v3;
        } else if (BN == 64) {
            int n = t >> 2, q = t & 3;
            const __bf16* src = WT + (size_t)(n0 + n) * 256 + k0 + q * 16;
            bf16x8 v0 = *(const bf16x8*)src;
            bf16x8 v1 = *(const bf16x8*)(src + 8);
            *(bf16x8*)&Wl[n][((q * 2 + 0) ^ (n & 7)) * 8] = v0;
            *(bf16x8*)&Wl[n][((q * 2 + 1) ^ (n & 7)) * 8] = v1;
        } else {
            if (t < 128) {
                int n = t >> 3, c = t & 7;
                bf16x8 v = *(const bf16x8*)(WT + (size_t)(n0 + n) * 256 + k0 + c * 8);
                *(bf16x8*)&Wl[n][(c ^ (n & 7)) * 8] = v;
            }
        }
        __syncthreads();
#pragma unroll
        for (int ks = 0; ks < 2; ks++) {
            int c = ks * 4 + (lane >> 4);
            bf16x8 af[MR];
#pragma unroll
            for (int mf = 0; mf < MR; mf++) {
                int i = wr + mf * 16 + (lane & 15);
                af[mf] = *(const bf16x8*)&Al[i][(c ^ (i & 7)) * 8];
            }
#pragma unroll
            for (int nf = 0; nf < NC; nf++) {
                int n = wc + nf * 16 + (lane & 15);
                bf16x8 bfr = *(const bf16x8*)&Wl[n][(c ^ (n & 7)) * 8];
#pragma unroll
                for (int mf = 0; mf < MR; mf++)
                    acc[mf][nf] = __builtin_amdgcn_mfma_f32_16x16x32_bf16(af[mf], bfr, acc[mf][nf], 0, 0, 0);
            }
        }
    }
    if (MODE == 3) {
        __syncthreads();
#pragma unroll
        for (int mf = 0; mf < MR; mf++) {
#pragma unroll
            for (int nf = 0; nf < NC; nf++) {
                int col = wc + nf * 16 + (lane & 15);
#pragma unroll
                for (int r = 0; r < 4; r++) {
                    int row = wr + mf * 16 + (lane >> 4) * 4 + r;
                    float v = acc[mf][nf][r] + bias[m0 + row];
                    smem[row * 128 + (((col >> 3) ^ (row & 15)) * 8) + (col & 7)] = (__bf16)v;
                }
            }
        }
        __syncthreads();
#pragma unroll
        for (int p = 0; p < 2; p++) {
            int row = p * 64 + (t >> 2);
            int cq = (t & 3) * 4;
            __bf16* dst = (__bf16*)Cv + c_z + (size_t)(m0 + row) * N + n0 + (t & 3) * 32;
#pragma unroll
            for (int u = 0; u < 4; u++) {
                int ch = (cq + u) ^ (row & 15);
                *(bf16x8*)(dst + u * 8) = *(const bf16x8*)&smem[row * 128 + ch * 8];
            }
        }
        return;
    }
#pragma unroll
    for (int mf = 0; mf < MR; mf++) {
#pragma unroll
        for (int nf = 0; nf < NC; nf++) {
            int col = n0 + wc + nf * 16 + (lane & 15);
            float bcol = bias[col] * bscale;
#pragma unroll
            for (int r = 0; r < 4; r++) {
                int row = m0 + wr + mf * 16 + (lane >> 4) * 4 + r;
                float v = acc[mf][nf][r] + bcol;
                if (relu) v = fmaxf(v, 0.f);
                if (MODE == 2) {
                    if (col < 64) ((__bf16*)Cv)[(size_t)row * 64 + col] = (__bf16)v;
                    else ((__bf16*)Cv2)[(size_t)row * 64 + (col - 64)] = (__bf16)v;
                } else if (MODE == 1) {
                    ((__bf16*)Cv)[(size_t)row * N + col] = (__bf16)v;
                } else {
                    ((float*)Cv)[(size_t)row * N + col] = v;
                }
            }
        }
    }
}

// ---------------- bias gemv (bf16 x): out[r] = x[r,:] . Wb[:,0] + bb[0]
__global__ __launch_bounds__(256) void bias_gemv(const __bf16* __restrict__ X,
                                                 const float* __restrict__ Wb,
                                                 const float* __restrict__ bb,
                                                 float* __restrict__ out) {
    int wave = threadIdx.x >> 6, lane = threadIdx.x & 63;
    size_t row = (size_t)blockIdx.x * 4 + wave;
    bf16x4 xv = *(const bf16x4*)(X + row * 256 + lane * 4);
    float4 wv = *(const float4*)(Wb + lane * 4);
    float p = (float)xv[0] * wv.x + (float)xv[1] * wv.y + (float)xv[2] * wv.z + (float)xv[3] * wv.w;
    for (int off = 32; off; off >>= 1) p += __shfl_down(p, off, 64);
    if (lane == 0) out[row] = p + bb[0];
}

// ---------------- MFMA fused attention + LN1 (8 waves, j-tile 64, 16x16 MFMA)
// R13-proven version (best measured): Kl/bsh in LDS, T14 async-stage + setprio, bf16 dataflow.
__global__ __launch_bounds__(512, 4) void attn_mfma(const __bf16* __restrict__ kb,
                                                    const __bf16* __restrict__ qb,
                                                    const __bf16* __restrict__ vT,
                                                    const float* __restrict__ biasb,
                                                    const __bf16* __restrict__ xinb,
                                                    const float* __restrict__ gamma,
                                                    const float* __restrict__ beta,
                                                    __bf16* __restrict__ outb) {
    int h = blockIdx.x;
    int blow = h & 7, rest = h >> 3;
    int ib = rest & 15;
    int b = blow + (rest >> 4) * 8;
    const int i0 = ib * 64;
    const int t = threadIdx.x;
    const int w = t >> 6, lane = t & 63;
    const int iq = w >> 1;
    const int dhalf = w & 1;

    __shared__ __align__(16) __bf16 Kl[64][64];
    __shared__ __align__(16) __bf16 Ql[64][64];
    __shared__ __align__(16) __bf16 Vl[256][64];
    __shared__ __align__(16) __bf16 Sl[64][64];
    __shared__ float bsh[64];
    __shared__ float rowred[2][64][2];

    const int qj = t >> 3, qc = t & 7;
    const __bf16* qsrc_base = qb + ((size_t)(b * SS + qj)) * 64 + qc * 8;
    const int vd = t >> 1, vjh = t & 1;
    const __bf16* vsrc_base = vT + ((size_t)b * 256 + vd) * SS + vjh * 32;

    {   // stage K once + bias
        int i = t >> 3, c = t & 7;
        bf16x8 v = *(const bf16x8*)(kb + ((size_t)(b * SS + i0 + i)) * 64 + c * 8);
        *(bf16x8*)&Kl[i][(c ^ (i & 7)) * 8] = v;
        if (t < 64) bsh[t] = biasb[b * SS + i0 + t];
    }
    {   // prologue: stage Q/V for j0=0
        bf16x8 qv = *(const bf16x8*)(qsrc_base);
        *(bf16x8*)&Ql[qj][(qc ^ (qj & 7)) * 8] = qv;
#pragma unroll
        for (int u = 0; u < 4; u++) {
            bf16x8 v = *(const bf16x8*)(vsrc_base + u * 8);
            *(bf16x8*)&Vl[vd][((vjh * 4 + u) ^ (vd & 7)) * 8] = v;
        }
    }
    __syncthreads();

    f32x4 acc[8] = {};

    for (int j0 = 0; j0 < SS; j0 += 64) {
        const bool has_next = (j0 + 64) < SS;
        bf16x8 qn;
        bf16x8 vn0, vn1, vn2, vn3;
        if (has_next) {
            qn = *(const bf16x8*)(qsrc_base + (size_t)(j0 + 64) * 64);
            const __bf16* vs = vsrc_base + j0 + 64;
            vn0 = *(const bf16x8*)(vs);
            vn1 = *(const bf16x8*)(vs + 8);
            vn2 = *(const bf16x8*)(vs + 16);
            vn3 = *(const bf16x8*)(vs + 24);
        }
        // ---- S phase
#pragma unroll
        for (int jj = 0; jj < 2; jj++) {
            int jq = (w & 1) * 2 + jj;
            f32x4 sacc = {0.f, 0.f, 0.f, 0.f};
            __builtin_amdgcn_s_setprio(1);
#pragma unroll
            for (int ks = 0; ks < 2; ks++) {
                int i = iq * 16 + (lane & 15);
                int ck = ks * 4 + (lane >> 4);
                bf16x8 a = *(const bf16x8*)&Kl[i][(ck ^ (i & 7)) * 8];
                int j = jq * 16 + (lane & 15);
                bf16x8 bq = *(const bf16x8*)&Ql[j][(ck ^ (j & 7)) * 8];
                sacc = __builtin_amdgcn_mfma_f32_16x16x32_bf16(a, bq, sacc, 0, 0, 0);
            }
            __builtin_amdgcn_s_setprio(0);
            int jcol = jq * 16 + (lane & 15);
#pragma unroll
            for (int r = 0; r < 4; r++) {
                int irow = iq * 16 + (lane >> 4) * 4 + r;
                float x = sacc[r] + bsh[irow];
                float sg = 1.f / (1.f + __expf(-x));
                Sl[irow][(((jcol >> 3) ^ (irow & 7)) * 8) + (jcol & 7)] = (__bf16)sg;
            }
        }
        __syncthreads();
        // ---- PV phase
        bf16x8 am[2];
#pragma unroll
        for (int m = 0; m < 2; m++) {
            int i = iq * 16 + (lane & 15);
            int cj = m * 4 + (lane >> 4);
            am[m] = *(const bf16x8*)&Sl[i][(cj ^ (i & 7)) * 8];
        }
        __builtin_amdgcn_s_setprio(1);
#pragma unroll
        for (int dq = 0; dq < 8; dq++) {
            int d = dhalf * 128 + dq * 16 + (lane & 15);
#pragma unroll
            for (int m = 0; m < 2; m++) {
                int cj = m * 4 + (lane >> 4);
                bf16x8 bv = *(const bf16x8*)&Vl[d][(cj ^ (d & 7)) * 8];
                acc[dq] = __builtin_amdgcn_mfma_f32_16x16x32_bf16(am[m], bv, acc[dq], 0, 0, 0);
            }
        }
        __builtin_amdgcn_s_setprio(0);
        __syncthreads();
        if (has_next) {
            *(bf16x8*)&Ql[qj][(qc ^ (qj & 7)) * 8] = qn;
            *(bf16x8*)&Vl[vd][((vjh * 4 + 0) ^ (vd & 7)) * 8] = vn0;
            *(bf16x8*)&Vl[vd][((vjh * 4 + 1) ^ (vd & 7)) * 8] = vn1;
            *(bf16x8*)&Vl[vd][((vjh * 4 + 2) ^ (vd & 7)) * 8] = vn2;
            *(bf16x8*)&Vl[vd][((vjh * 4 + 3) ^ (vd & 7)) * 8] = vn3;
            __syncthreads();
        }
    }

    // ---- fused LN1 epilogue (bf16 residual)
#pragma unroll
    for (int r = 0; r < 4; r++) {
        int il = iq * 16 + (lane >> 4) * 4 + r;
        size_t rowoff = ((size_t)(b * SS + i0 + il)) * 256 + dhalf * 128 + (lane & 15);
#pragma unroll
        for (int dq = 0; dq < 8; dq++)
            acc[dq][r] += (float)xinb[rowoff + dq * 16];
    }
    float sr[4], qr[4];
#pragma unroll
    for (int r = 0; r < 4; r++) {
        float s = 0.f, q = 0.f;
#pragma unroll
        for (int dq = 0; dq < 8; dq++) {
            float v = acc[dq][r];
            s += v; q += v * v;
        }
#pragma unroll
        for (int mask = 8; mask; mask >>= 1) {
            s += __shfl_xor(s, mask, 64);
            q += __shfl_xor(q, mask, 64);
        }
        sr[r] = s; qr[r] = q;
    }
    if ((lane & 15) == 0) {
#pragma unroll
        for (int r = 0; r < 4; r++) {
            int il = iq * 16 + (lane >> 4) * 4 + r;
            rowred[dhalf][il][0] = sr[r];
            rowred[dhalf][il][1] = qr[r];
        }
    }
    __syncthreads();
    float gv[8], bv2[8];
#pragma unroll
    for (int dq = 0; dq < 8; dq++) {
        int d = dhalf * 128 + dq * 16 + (lane & 15);
        gv[dq] = gamma[d];
        bv2[dq] = beta[d];
    }
#pragma unroll
    for (int r = 0; r < 4; r++) {
        int il = iq * 16 + (lane >> 4) * 4 + r;
        float st = rowred[0][il][0] + rowred[1][il][0];
        float qt = rowred[0][il][1] + rowred[1][il][1];
        float mean = st * (1.f / 256.f);
        float var = qt * (1.f / 256.f) - mean * mean;
        float inv = 1.f / sqrtf(var + LEPS);
        size_t rowoff = ((size_t)(b * SS + i0 + il)) * 256 + dhalf * 128 + (lane & 15);
#pragma unroll
        for (int dq = 0; dq < 8; dq++) {
            float o = (acc[dq][r] - mean) * inv * gv[dq] + bv2[dq];
            outb[rowoff + dq * 16] = (__bf16)o;
        }
    }
}

// ---------------- ff GEMM (BM=64, BN=256, 8 waves, grid 512) + fused LN2 (no affine)
__global__ __launch_bounds__(512) void gemm_ff_ln2(const __bf16* __restrict__ A,
                                                   const __bf16* __restrict__ WT,
                                                   const float* __restrict__ bias,
                                                   const __bf16* __restrict__ resid,
                                                   __bf16* __restrict__ outb) {
    const int t = threadIdx.x;
    const int w = t >> 6, lane = t & 63;
    const int m0 = blockIdx.x * 64;
    const int wr = (w >> 2) * 32, wc = (w & 3) * 64;
    __shared__ __align__(16) __bf16 Al[64][64];
    __shared__ __align__(16) __bf16 Wl[256][64];
    __shared__ float rowred[4][64][2];
    f32x4 acc[2][4] = {};

    for (int k0 = 0; k0 < 256; k0 += 64) {
        __syncthreads();
        {
            int r = t >> 3, c = t & 7;
            bf16x8 v = *(const bf16x8*)(A + (size_t)(m0 + r) * 256 + k0 + c * 8);
            *(bf16x8*)&Al[r][(c ^ (r & 7)) * 8] = v;
        }
        {
            int n = t >> 1, c0 = (t & 1) * 4;
            const __bf16* src = WT + (size_t)n * 256 + k0 + c0 * 8;
#pragma unroll
            for (int u = 0; u < 4; u++) {
                bf16x8 v = *(const bf16x8*)(src + u * 8);
                *(bf16x8*)&Wl[n][((c0 + u) ^ (n & 7)) * 8] = v;
            }
        }
        __syncthreads();
#pragma unroll
        for (int ks = 0; ks < 2; ks++) {
            int c = ks * 4 + (lane >> 4);
            bf16x8 af[2];
#pragma unroll
            for (int mf = 0; mf < 2; mf++) {
                int i = wr + mf * 16 + (lane & 15);
                af[mf] = *(const bf16x8*)&Al[i][(c ^ (i & 7)) * 8];
            }
#pragma unroll
            for (int nf = 0; nf < 4; nf++) {
                int n = wc + nf * 16 + (lane & 15);
                bf16x8 bfr = *(const bf16x8*)&Wl[n][(c ^ (n & 7)) * 8];
#pragma unroll
                for (int mf = 0; mf < 2; mf++)
                    acc[mf][nf] = __builtin_amdgcn_mfma_f32_16x16x32_bf16(af[mf], bfr, acc[mf][nf], 0, 0, 0);
            }
        }
    }
    float colb[4];
#pragma unroll
    for (int nf = 0; nf < 4; nf++) colb[nf] = bias[wc + nf * 16 + (lane & 15)];
#pragma unroll
    for (int mf = 0; mf < 2; mf++) {
#pragma unroll
        for (int r = 0; r < 4; r++) {
            int rl = wr + mf * 16 + (lane >> 4) * 4 + r;
            const __bf16* rrow = resid + (size_t)(m0 + rl) * 256 + wc + (lane & 15);
            float s = 0.f, q = 0.f;
#pragma unroll
            for (int nf = 0; nf < 4; nf++) {
                float v = fmaxf(acc[mf][nf][r] + colb[nf], 0.f) + (float)rrow[nf * 16];
                acc[mf][nf][r] = v;
                s += v; q += v * v;
            }
#pragma unroll
            for (int msk = 1; msk <= 8; msk <<= 1) {
                s += __shfl_xor(s, msk, 64);
                q += __shfl_xor(q, msk, 64);
            }
            if ((lane & 15) == 0) {
                rowred[w & 3][rl][0] = s;
                rowred[w & 3][rl][1] = q;
            }
        }
    }
    __syncthreads();
#pragma unroll
    for (int mf = 0; mf < 2; mf++) {
#pragma unroll
        for (int r = 0; r < 4; r++) {
            int rl = wr + mf * 16 + (lane >> 4) * 4 + r;
            float s = rowred[0][rl][0] + rowred[1][rl][0] + rowred[2][rl][0] + rowred[3][rl][0];
            float q = rowred[0][rl][1] + rowred[1][rl][1] + rowred[2][rl][1] + rowred[3][rl][1];
            float mean = s * (1.f / 256.f);
            float var = q * (1.f / 256.f) - mean * mean;
            float inv = 1.f / sqrtf(var + LEPS);
            size_t base = (size_t)(m0 + rl) * 256 + wc + (lane & 15);
#pragma unroll
            for (int nf = 0; nf < 4; nf++) {
                float o = (acc[mf][nf][r] - mean) * inv;
                outb[base + nf * 16] = (__bf16)o;
            }
        }
    }
}

// ---------------- pooling P1: per-(b,h) softmax -> normalized weights
__global__ __launch_bounds__(256) void pool_softmax(const float* __restrict__ pk,
                                                    const float* __restrict__ queries,
                                                    float* __restrict__ wout) {
    const int b = blockIdx.x, h = blockIdx.y;
    const int t = threadIdx.x;
    const int wv = t >> 6, lane = t & 63;
    __shared__ float qv[16];
    __shared__ float redm[4], reds[4];
    if (t < 16) qv[t] = queries[h * 16 + t];
    __syncthreads();
    float sc[4];
#pragma unroll
    for (int c = 0; c < 4; c++) {
        int s = c * 256 + t;
        const float* p = pk + ((size_t)b * SS + s) * 16;
        float4 a0 = *(const float4*)p;
        float4 a1 = *(const float4*)(p + 4);
        float4 a2 = *(const float4*)(p + 8);
        float4 a3 = *(const float4*)(p + 12);
        sc[c] = a0.x * qv[0] + a0.y * qv[1] + a0.z * qv[2] + a0.w * qv[3]
              + a1.x * qv[4] + a1.y * qv[5] + a1.z * qv[6] + a1.w * qv[7]
              + a2.x * qv[8] + a2.y * qv[9] + a2.z * qv[10] + a2.w * qv[11]
              + a3.x * qv[12] + a3.y * qv[13] + a3.z * qv[14] + a3.w * qv[15];
    }
    float m = fmaxf(fmaxf(sc[0], sc[1]), fmaxf(sc[2], sc[3]));
    for (int off = 32; off; off >>= 1) m = fmaxf(m, __shfl_xor(m, off, 64));
    if (lane == 0) redm[wv] = m;
    __syncthreads();
    m = fmaxf(fmaxf(redm[0], redm[1]), fmaxf(redm[2], redm[3]));
    float e[4];
    float sum = 0.f;
#pragma unroll
    for (int c = 0; c < 4; c++) { e[c] = expf(sc[c] - m); sum += e[c]; }
    for (int off = 32; off; off >>= 1) sum += __shfl_xor(sum, off, 64);
    if (lane == 0) reds[wv] = sum;
    __syncthreads();
    float inv = 1.f / (reds[0] + reds[1] + reds[2] + reds[3]);
#pragma unroll
    for (int c = 0; c < 4; c++)
        wout[((size_t)(b * 4 + h)) * SS + c * 256 + t] = e[c] * inv;
}

// ---------------- pooling P2: partial weighted sums over s-chunks of 64
__global__ __launch_bounds__(256) void pool_wsum(const float* __restrict__ wgt,
                                                 const float* __restrict__ pv,
                                                 float* __restrict__ partial) {
    const int b = blockIdx.x, c = blockIdx.y;
    const int h = threadIdx.x >> 6, d = threadIdx.x & 63;
    const float* wrow = wgt + ((size_t)(b * 4 + h)) * SS + c * 64;
    const float* pvb = pv + ((size_t)(b * SS + c * 64)) * 64 + d;
    float a = 0.f;
#pragma unroll 8
    for (int s = 0; s < 64; s++) a += wrow[s] * pvb[(size_t)s * 64];
    partial[((size_t)b * 16 + c) * 256 + threadIdx.x] = a;
}

// ---------------- pooling P3: reduce partials + final linear
__global__ __launch_bounds__(256) void pool_final(const float* __restrict__ partial,
                                                  const float* __restrict__ W1,
                                                  const float* __restrict__ b1,
                                                  float* __restrict__ out) {
    const int b = blockIdx.x, t = threadIdx.x;
    __shared__ float r0[256], r1[256];
    float a = 0.f;
#pragma unroll
    for (int c = 0; c < 16; c++) a += partial[((size_t)b * 16 + c) * 256 + t];
    r0[t] = a * W1[t * 2 + 0];
    r1[t] = a * W1[t * 2 + 1];
    __syncthreads();
    for (int off = 128; off > 0; off >>= 1) {
        if (t < off) { r0[t] += r0[t + off]; r1[t] += r1[t + off]; }
        __syncthreads();
    }
    if (t == 0) {
        out[b * 2 + 0] = r0[0] + b1[0];
        out[b * 2 + 1] = r1[0] + b1[1];
    }
}

extern "C" void kernel_launch(void* const* d_in, const int* in_sizes, int n_in,
                              void* d_out, int out_size, void* d_ws, size_t ws_size,
                              hipStream_t stream) {
    const float* input = (const float*)d_in[0];
    const float* eWk = (const float*)d_in[3];
    const float* ebk = (const float*)d_in[4];
    const float* eWq = (const float*)d_in[5];
    const float* ebq = (const float*)d_in[6];
    const float* eWv = (const float*)d_in[7];
    const float* ebv = (const float*)d_in[8];
    const float* eWb = (const float*)d_in[9];
    const float* ebb = (const float*)d_in[10];
    const float* eWff = (const float*)d_in[11];
    const float* ebff = (const float*)d_in[12];
    const float* eg1 = (const float*)d_in[13];
    const float* ebe1 = (const float*)d_in[14];
    const float* pWk = (const float*)d_in[15];
    const float* pbk = (const float*)d_in[16];
    const float* pWv = (const float*)d_in[17];
    const float* pbv = (const float*)d_in[18];
    const float* qrs = (const float*)d_in[19];
    const float* W1 = (const float*)d_in[20];
    const float* b1 = (const float*)d_in[21];
    float* out = (float*)d_out;

    // ---- workspace layout (bf16-only inter-kernel dataflow)
    float* ws = (float*)d_ws;
    float* xbuf = ws;                               // (reserved)
    __bf16* xbf = (__bf16*)(xbuf + (size_t)MM * DD);      // MM*256 bf16 — THE x
    float* tmp2 = (float*)(xbf + (size_t)MM * DD);        // tail scratch
    float* r3 = tmp2 + (size_t)MM * DD;
    __bf16* tmp2bf = (__bf16*)r3;                   //   LN1 bf16 (attn epilogue)
    __bf16* vTb = tmp2bf + (size_t)MM * DD;         //   vT [B][256][1024]
    float* r4 = r3 + (size_t)MM * DD;
    __bf16* kbf = (__bf16*)r4;                      //   k bf16
    __bf16* qbf = kbf + (size_t)MM * 64;            //   q bf16
    float* bbuf = r4 + (size_t)MM * (DD / 2);       // MM f32
    __bf16* wbf = (__bf16*)(bbuf + MM);             // weights bf16

    __bf16* WkqT = wbf;                     // [4][128][256]
    __bf16* WvT = WkqT + 4 * 128 * 256;     // [4][256][256]
    __bf16* WffT = WvT + 4 * 256 * 256;     // [4][256][256]
    __bf16* pWkT = WffT + 4 * 256 * 256;    // [16][256], pre-scaled
    __bf16* pWvT = pWkT + 16 * 256;         // [64][256]
    float* biasc = (float*)(pWvT + 64 * 256);  // [4][128]

    // tail-phase buffers inside tmp2 region
    float* pkbuf = tmp2;                        // MM*16
    float* pvbuf = tmp2 + (size_t)MM * 16;      // MM*64
    float* wgtbuf = tmp2 + (size_t)MM * 80;     // 32*4*1024
    float* partial = wgtbuf + (size_t)BB * 4 * SS;  // 32*16*256

    const float SC = 0.125f;  // 1/sqrt(64)

    cast_wt<<<dim3(64, 1, 4), 256, 0, stream>>>(eWk, WkqT, 64, SC, 128 * 256, 0);
    cast_wt<<<dim3(64, 1, 4), 256, 0, stream>>>(eWq, WkqT, 64, 1.f, 128 * 256, 64);
    cast_wt<<<dim3(256, 1, 4), 256, 0, stream>>>(eWv, WvT, 256, 1.f, 256 * 256, 0);
    cast_wt<<<dim3(256, 1, 4), 256, 0, stream>>>(eWff, WffT, 256, 1.f, 256 * 256, 0);
    cast_wt<<<dim3(16, 1, 1), 256, 0, stream>>>(pWk, pWkT, 16, SC, 16 * 256, 0);
    cast_wt<<<dim3(64, 1, 1), 256, 0, stream>>>(pWv, pWvT, 64, 1.f, 64 * 256, 0);
    bias_combine<<<4, 128, 0, stream>>>(ebk, ebq, biasc);
    cast_x<<<MM * DD / (256 * 8), 256, 0, stream>>>(input, xbf);

    for (int l = 0; l < 4; l++) {
        gemm_mfma<128, 2><<<dim3(MM / 128, 1), 256, 0, stream>>>(
            xbf, WkqT + (size_t)l * 128 * 256, biasc + l * 128, 1.f, 0, kbf, qbf, 64);
        gemm_mfma<128, 3><<<dim3(2, SS / 128, BB), 256, 0, stream>>>(
            WvT + (size_t)l * 256 * 256, xbf, ebv + l * DD, 1.f, 0, vTb, nullptr, SS);
        bias_gemv<<<MM / 4, 256, 0, stream>>>(xbf, eWb + (size_t)l * DD, ebb + l, bbuf);
        attn_mfma<<<dim3(512, 1), 512, 0, stream>>>(kbf, qbf, vTb, bbuf, xbf,
                                                    eg1 + l * DD, ebe1 + l * DD, tmp2bf);
        gemm_ff_ln2<<<dim3(MM / 64, 1), 512, 0, stream>>>(
            tmp2bf, WffT + (size_t)l * 256 * 256, ebff + l * DD, tmp2bf, xbf);
    }
    gemm_mfma<16, 0><<<dim3(MM / 128, 1), 256, 0, stream>>>(xbf, pWkT, pbk, SC, 0, pkbuf, nullptr, 16);
    gemm_mfma<64, 0><<<dim3(MM / 128, 1), 256, 0, stream>>>(xbf, pWvT, pbv, 1.f, 0, pvbuf, nullptr, 64);
    pool_softmax<<<dim3(BB, 4), 256, 0, stream>>>(pkbuf, qrs, wgtbuf);
    pool_wsum<<<dim3(BB, 16), 256, 0, stream>>>(wgtbuf, pvbuf, partial);
    pool_final<<<BB, 256, 0, stream>>>(partial, W1, b1, out);
}

// Round 16
// 418.295 us; speedup vs baseline: 1.0773x; 1.0521x over previous
//
#include <hip/hip_runtime.h>
#include <hip/hip_bf16.h>
#include <math.h>

#define BB 32
#define SS 1024
#define DD 256
#define MM (BB*SS)   // 32768
#define LEPS 1e-5f

typedef __bf16 bf16x8 __attribute__((ext_vector_type(8)));
typedef __bf16 bf16x4 __attribute__((ext_vector_type(4)));
typedef float f32x4 __attribute__((ext_vector_type(4)));

// ---------------- weight cast+transpose: dst[l*dstride + (n+noff)*256 + k] = W[l][k][n]*scale
__global__ __launch_bounds__(256) void cast_wt(const float* __restrict__ W,
                                               __bf16* __restrict__ WT,
                                               int N, float scale, int dstride, int noff) {
    int n = blockIdx.x, l = blockIdx.z, k = threadIdx.x;
    WT[(size_t)dstride * l + (size_t)(n + noff) * 256 + k] =
        (__bf16)(W[(size_t)256 * N * l + (size_t)k * N + n] * scale);
}

// ---------------- combined k/q bias: dst[l][j] = j<64 ? bk*SC : bq
__global__ __launch_bounds__(128) void bias_combine(const float* __restrict__ bk,
                                                    const float* __restrict__ bq,
                                                    float* __restrict__ dst) {
    int l = blockIdx.x, j = threadIdx.x;
    dst[l * 128 + j] = (j < 64) ? bk[l * 64 + j] * 0.125f : bq[l * 64 + (j - 64)];
}

// ---------------- cast fp32 -> bf16, 8 elems/thread
__global__ __launch_bounds__(256) void cast_x(const float* __restrict__ x, __bf16* __restrict__ xb) {
    size_t i = ((size_t)blockIdx.x * 256 + threadIdx.x) * 8;
    float4 a = *(const float4*)(x + i);
    float4 b = *(const float4*)(x + i + 4);
    __bf16 o[8] __attribute__((aligned(16)));
    o[0] = (__bf16)a.x; o[1] = (__bf16)a.y; o[2] = (__bf16)a.z; o[3] = (__bf16)a.w;
    o[4] = (__bf16)b.x; o[5] = (__bf16)b.y; o[6] = (__bf16)b.z; o[7] = (__bf16)b.w;
    *(bf16x8*)(xb + i) = *(bf16x8*)o;
}

// ---------------- fused per-layer kq-GEMM + vT-producer (768 blocks, 256 thr)
// blocks [0,256): kq:  C[kq] = x @ WkqT^T + biasc, split cols to kq0/kq1 (stride 64)
// blocks [256,768): vT: vT[b][d][s] = WvT[d,:] . x[b,s,:] + bv[d], LDS-bounce stores
__global__ __launch_bounds__(256) void gemm_kq_vt(const __bf16* __restrict__ xbf,
                                                  const __bf16* __restrict__ WkqT,
                                                  const float* __restrict__ biasc,
                                                  __bf16* __restrict__ kq0,
                                                  __bf16* __restrict__ kq1,
                                                  const __bf16* __restrict__ WvT,
                                                  const float* __restrict__ bv,
                                                  __bf16* __restrict__ vTb) {
    const int t = threadIdx.x;
    const int w = t >> 6, lane = t & 63;
    const int wr = (w >> 1) * 64;
    const int wc = (w & 1) * 64;
    __shared__ __align__(16) __bf16 smem[128 * 64 + 128 * 64];
    __bf16 (*Al)[64] = (__bf16(*)[64])smem;
    __bf16 (*Wl)[64] = (__bf16(*)[64])(smem + 128 * 64);
    f32x4 acc[4][4] = {};

    const bool is_kq = (blockIdx.x < 256);
    const __bf16* A;
    const __bf16* WT;
    size_t wt_z = 0, c_z = 0;
    int m0, n0;
    if (is_kq) {
        A = xbf; WT = WkqT;
        m0 = blockIdx.x * 128; n0 = 0;
    } else {
        int v = blockIdx.x - 256;
        int bxv = v & 1, by = (v >> 1) & 7, bz = v >> 4;
        A = WvT; WT = xbf;
        m0 = bxv * 128; n0 = by * 128;
        wt_z = (size_t)bz * SS * 256;
        c_z = (size_t)bz * 256 * (size_t)SS;
    }

    for (int k0 = 0; k0 < 256; k0 += 64) {
        __syncthreads();
        {
            int r = t >> 1, half = t & 1;
            const __bf16* src = A + (size_t)(m0 + r) * 256 + k0 + half * 32;
            bf16x8 v0 = *(const bf16x8*)(src);
            bf16x8 v1 = *(const bf16x8*)(src + 8);
            bf16x8 v2 = *(const bf16x8*)(src + 16);
            bf16x8 v3 = *(const bf16x8*)(src + 24);
            int cb = half * 4;
            *(bf16x8*)&Al[r][((cb + 0) ^ (r & 7)) * 8] = v0;
            *(bf16x8*)&Al[r][((cb + 1) ^ (r & 7)) * 8] = v1;
            *(bf16x8*)&Al[r][((cb + 2) ^ (r & 7)) * 8] = v2;
            *(bf16x8*)&Al[r][((cb + 3) ^ (r & 7)) * 8] = v3;
        }
        {
            int r = t >> 1, half = t & 1;
            const __bf16* src = WT + wt_z + (size_t)(n0 + r) * 256 + k0 + half * 32;
            bf16x8 v0 = *(const bf16x8*)(src);
            bf16x8 v1 = *(const bf16x8*)(src + 8);
            bf16x8 v2 = *(const bf16x8*)(src + 16);
            bf16x8 v3 = *(const bf16x8*)(src + 24);
            int cb = half * 4;
            *(bf16x8*)&Wl[r][((cb + 0) ^ (r & 7)) * 8] = v0;
            *(bf16x8*)&Wl[r][((cb + 1) ^ (r & 7)) * 8] = v1;
            *(bf16x8*)&Wl[r][((cb + 2) ^ (r & 7)) * 8] = v2;
            *(bf16x8*)&Wl[r][((cb + 3) ^ (r & 7)) * 8] = v3;
        }
        __syncthreads();
#pragma unroll
        for (int ks = 0; ks < 2; ks++) {
            int c = ks * 4 + (lane >> 4);
            bf16x8 af[4];
#pragma unroll
            for (int mf = 0; mf < 4; mf++) {
                int i = wr + mf * 16 + (lane & 15);
                af[mf] = *(const bf16x8*)&Al[i][(c ^ (i & 7)) * 8];
            }
#pragma unroll
            for (int nf = 0; nf < 4; nf++) {
                int n = wc + nf * 16 + (lane & 15);
                bf16x8 bfr = *(const bf16x8*)&Wl[n][(c ^ (n & 7)) * 8];
#pragma unroll
                for (int mf = 0; mf < 4; mf++)
                    acc[mf][nf] = __builtin_amdgcn_mfma_f32_16x16x32_bf16(af[mf], bfr, acc[mf][nf], 0, 0, 0);
            }
        }
    }
    if (is_kq) {
        // kq split epilogue
#pragma unroll
        for (int mf = 0; mf < 4; mf++) {
#pragma unroll
            for (int nf = 0; nf < 4; nf++) {
                int col = wc + nf * 16 + (lane & 15);
                float bcol = biasc[col];
#pragma unroll
                for (int r = 0; r < 4; r++) {
                    int row = m0 + wr + mf * 16 + (lane >> 4) * 4 + r;
                    float v = acc[mf][nf][r] + bcol;
                    if (col < 64) kq0[(size_t)row * 64 + col] = (__bf16)v;
                    else kq1[(size_t)row * 64 + (col - 64)] = (__bf16)v;
                }
            }
        }
    } else {
        // vT LDS-bounce epilogue
        __syncthreads();
#pragma unroll
        for (int mf = 0; mf < 4; mf++) {
#pragma unroll
            for (int nf = 0; nf < 4; nf++) {
                int col = wc + nf * 16 + (lane & 15);
#pragma unroll
                for (int r = 0; r < 4; r++) {
                    int row = wr + mf * 16 + (lane >> 4) * 4 + r;
                    float v = acc[mf][nf][r] + bv[m0 + row];
                    smem[row * 128 + (((col >> 3) ^ (row & 15)) * 8) + (col & 7)] = (__bf16)v;
                }
            }
        }
        __syncthreads();
#pragma unroll
        for (int p = 0; p < 2; p++) {
            int row = p * 64 + (t >> 2);
            int cq = (t & 3) * 4;
            __bf16* dst = vTb + c_z + (size_t)(m0 + row) * SS + n0 + (t & 3) * 32;
#pragma unroll
            for (int u = 0; u < 4; u++) {
                int ch = (cq + u) ^ (row & 15);
                *(bf16x8*)(dst + u * 8) = *(const bf16x8*)&smem[row * 128 + ch * 8];
            }
        }
    }
}

// ---------------- MFMA GEMM (tail only): C = A[M,256] @ WT[N,256]^T + bias
template <int BN, int MODE>
__global__ __launch_bounds__(256) void gemm_mfma(const __bf16* __restrict__ A,
                                                 const __bf16* __restrict__ WT,
                                                 const float* __restrict__ bias,
                                                 float bscale, int relu,
                                                 void* __restrict__ Cv, void* __restrict__ Cv2,
                                                 int N) {
    constexpr int MR = (BN == 128) ? 4 : 2;
    constexpr int NC = (BN == 128) ? 4 : BN / 16;
    const int t = threadIdx.x;
    const int w = t >> 6, lane = t & 63;
    const int m0 = blockIdx.x * 128;
    const int n0 = blockIdx.y * BN;
    const int wr = (BN == 128) ? (w >> 1) * 64 : w * 32;
    const int wc = (BN == 128) ? (w & 1) * 64 : 0;
    __shared__ __align__(16) __bf16 smem[128 * 64 + BN * 64];
    __bf16 (*Al)[64] = (__bf16(*)[64])smem;
    __bf16 (*Wl)[64] = (__bf16(*)[64])(smem + 128 * 64);
    f32x4 acc[MR][NC] = {};

    for (int k0 = 0; k0 < 256; k0 += 64) {
        __syncthreads();
        {
            int r = t >> 1, half = t & 1;
            const __bf16* src = A + (size_t)(m0 + r) * 256 + k0 + half * 32;
            bf16x8 v0 = *(const bf16x8*)(src);
            bf16x8 v1 = *(const bf16x8*)(src + 8);
            bf16x8 v2 = *(const bf16x8*)(src + 16);
            bf16x8 v3 = *(const bf16x8*)(src + 24);
            int cb = half * 4;
            *(bf16x8*)&Al[r][((cb + 0) ^ (r & 7)) * 8] = v0;
            *(bf16x8*)&Al[r][((cb + 1) ^ (r & 7)) * 8] = v1;
            *(bf16x8*)&Al[r][((cb + 2) ^ (r & 7)) * 8] = v2;
            *(bf16x8*)&Al[r][((cb + 3) ^ (r & 7)) * 8] = v3;
        }
        if (BN == 64) {
            int n = t >> 2, q = t & 3;
            const __bf16* src = WT + (size_t)(n0 + n) * 256 + k0 + q * 16;
            bf16x8 v0 = *(const bf16x8*)src;
            bf16x8 v1 = *(const bf16x8*)(src + 8);
            *(bf16x8*)&Wl[n][((q * 2 + 0) ^ (n & 7)) * 8] = v0;
            *(bf16x8*)&Wl[n][((q * 2 + 1) ^ (n & 7)) * 8] = v1;
        } else {
            if (t < 128) {
                int n = t >> 3, c = t & 7;
                bf16x8 v = *(const bf16x8*)(WT + (size_t)(n0 + n) * 256 + k0 + c * 8);
                *(bf16x8*)&Wl[n][(c ^ (n & 7)) * 8] = v;
            }
        }
        __syncthreads();
#pragma unroll
        for (int ks = 0; ks < 2; ks++) {
            int c = ks * 4 + (lane >> 4);
            bf16x8 af[MR];
#pragma unroll
            for (int mf = 0; mf < MR; mf++) {
                int i = wr + mf * 16 + (lane & 15);
                af[mf] = *(const bf16x8*)&Al[i][(c ^ (i & 7)) * 8];
            }
#pragma unroll
            for (int nf = 0; nf < NC; nf++) {
                int n = wc + nf * 16 + (lane & 15);
                bf16x8 bfr = *(const bf16x8*)&Wl[n][(c ^ (n & 7)) * 8];
#pragma unroll
                for (int mf = 0; mf < MR; mf++)
                    acc[mf][nf] = __builtin_amdgcn_mfma_f32_16x16x32_bf16(af[mf], bfr, acc[mf][nf], 0, 0, 0);
            }
        }
    }
#pragma unroll
    for (int mf = 0; mf < MR; mf++) {
#pragma unroll
        for (int nf = 0; nf < NC; nf++) {
            int col = n0 + wc + nf * 16 + (lane & 15);
            float bcol = bias[col] * bscale;
#pragma unroll
            for (int r = 0; r < 4; r++) {
                int row = m0 + wr + mf * 16 + (lane >> 4) * 4 + r;
                float v = acc[mf][nf][r] + bcol;
                if (relu) v = fmaxf(v, 0.f);
                ((float*)Cv)[(size_t)row * N + col] = v;
            }
        }
    }
}

// ---------------- bias gemv (bf16 x): out[r] = x[r,:] . Wb[:,0] + bb[0]
__global__ __launch_bounds__(256) void bias_gemv(const __bf16* __restrict__ X,
                                                 const float* __restrict__ Wb,
                                                 const float* __restrict__ bb,
                                                 float* __restrict__ out) {
    int wave = threadIdx.x >> 6, lane = threadIdx.x & 63;
    size_t row = (size_t)blockIdx.x * 4 + wave;
    bf16x4 xv = *(const bf16x4*)(X + row * 256 + lane * 4);
    float4 wv = *(const float4*)(Wb + lane * 4);
    float p = (float)xv[0] * wv.x + (float)xv[1] * wv.y + (float)xv[2] * wv.z + (float)xv[3] * wv.w;
    for (int off = 32; off; off >>= 1) p += __shfl_down(p, off, 64);
    if (lane == 0) out[row] = p + bb[0];
}

// ---------------- MFMA fused attention + LN1 (8 waves, j-tile 64, 16x16 MFMA)
// R13-proven version (best measured): Kl/bsh in LDS, T14 async-stage + setprio, bf16 dataflow.
__global__ __launch_bounds__(512, 4) void attn_mfma(const __bf16* __restrict__ kb,
                                                    const __bf16* __restrict__ qb,
                                                    const __bf16* __restrict__ vT,
                                                    const float* __restrict__ biasb,
                                                    const __bf16* __restrict__ xinb,
                                                    const float* __restrict__ gamma,
                                                    const float* __restrict__ beta,
                                                    __bf16* __restrict__ outb) {
    int h = blockIdx.x;
    int blow = h & 7, rest = h >> 3;
    int ib = rest & 15;
    int b = blow + (rest >> 4) * 8;
    const int i0 = ib * 64;
    const int t = threadIdx.x;
    const int w = t >> 6, lane = t & 63;
    const int iq = w >> 1;
    const int dhalf = w & 1;

    __shared__ __align__(16) __bf16 Kl[64][64];
    __shared__ __align__(16) __bf16 Ql[64][64];
    __shared__ __align__(16) __bf16 Vl[256][64];
    __shared__ __align__(16) __bf16 Sl[64][64];
    __shared__ float bsh[64];
    __shared__ float rowred[2][64][2];

    const int qj = t >> 3, qc = t & 7;
    const __bf16* qsrc_base = qb + ((size_t)(b * SS + qj)) * 64 + qc * 8;
    const int vd = t >> 1, vjh = t & 1;
    const __bf16* vsrc_base = vT + ((size_t)b * 256 + vd) * SS + vjh * 32;

    {   // stage K once + bias
        int i = t >> 3, c = t & 7;
        bf16x8 v = *(const bf16x8*)(kb + ((size_t)(b * SS + i0 + i)) * 64 + c * 8);
        *(bf16x8*)&Kl[i][(c ^ (i & 7)) * 8] = v;
        if (t < 64) bsh[t] = biasb[b * SS + i0 + t];
    }
    {   // prologue: stage Q/V for j0=0
        bf16x8 qv = *(const bf16x8*)(qsrc_base);
        *(bf16x8*)&Ql[qj][(qc ^ (qj & 7)) * 8] = qv;
#pragma unroll
        for (int u = 0; u < 4; u++) {
            bf16x8 v = *(const bf16x8*)(vsrc_base + u * 8);
            *(bf16x8*)&Vl[vd][((vjh * 4 + u) ^ (vd & 7)) * 8] = v;
        }
    }
    __syncthreads();

    f32x4 acc[8] = {};

    for (int j0 = 0; j0 < SS; j0 += 64) {
        const bool has_next = (j0 + 64) < SS;
        bf16x8 qn;
        bf16x8 vn0, vn1, vn2, vn3;
        if (has_next) {
            qn = *(const bf16x8*)(qsrc_base + (size_t)(j0 + 64) * 64);
            const __bf16* vs = vsrc_base + j0 + 64;
            vn0 = *(const bf16x8*)(vs);
            vn1 = *(const bf16x8*)(vs + 8);
            vn2 = *(const bf16x8*)(vs + 16);
            vn3 = *(const bf16x8*)(vs + 24);
        }
        // ---- S phase
#pragma unroll
        for (int jj = 0; jj < 2; jj++) {
            int jq = (w & 1) * 2 + jj;
            f32x4 sacc = {0.f, 0.f, 0.f, 0.f};
            __builtin_amdgcn_s_setprio(1);
#pragma unroll
            for (int ks = 0; ks < 2; ks++) {
                int i = iq * 16 + (lane & 15);
                int ck = ks * 4 + (lane >> 4);
                bf16x8 a = *(const bf16x8*)&Kl[i][(ck ^ (i & 7)) * 8];
                int j = jq * 16 + (lane & 15);
                bf16x8 bq = *(const bf16x8*)&Ql[j][(ck ^ (j & 7)) * 8];
                sacc = __builtin_amdgcn_mfma_f32_16x16x32_bf16(a, bq, sacc, 0, 0, 0);
            }
            __builtin_amdgcn_s_setprio(0);
            int jcol = jq * 16 + (lane & 15);
#pragma unroll
            for (int r = 0; r < 4; r++) {
                int irow = iq * 16 + (lane >> 4) * 4 + r;
                float x = sacc[r] + bsh[irow];
                float sg = 1.f / (1.f + __expf(-x));
                Sl[irow][(((jcol >> 3) ^ (irow & 7)) * 8) + (jcol & 7)] = (__bf16)sg;
            }
        }
        __syncthreads();
        // ---- PV phase
        bf16x8 am[2];
#pragma unroll
        for (int m = 0; m < 2; m++) {
            int i = iq * 16 + (lane & 15);
            int cj = m * 4 + (lane >> 4);
            am[m] = *(const bf16x8*)&Sl[i][(cj ^ (i & 7)) * 8];
        }
        __builtin_amdgcn_s_setprio(1);
#pragma unroll
        for (int dq = 0; dq < 8; dq++) {
            int d = dhalf * 128 + dq * 16 + (lane & 15);
#pragma unroll
            for (int m = 0; m < 2; m++) {
                int cj = m * 4 + (lane >> 4);
                bf16x8 bv = *(const bf16x8*)&Vl[d][(cj ^ (d & 7)) * 8];
                acc[dq] = __builtin_amdgcn_mfma_f32_16x16x32_bf16(am[m], bv, acc[dq], 0, 0, 0);
            }
        }
        __builtin_amdgcn_s_setprio(0);
        __syncthreads();
        if (has_next) {
            *(bf16x8*)&Ql[qj][(qc ^ (qj & 7)) * 8] = qn;
            *(bf16x8*)&Vl[vd][((vjh * 4 + 0) ^ (vd & 7)) * 8] = vn0;
            *(bf16x8*)&Vl[vd][((vjh * 4 + 1) ^ (vd & 7)) * 8] = vn1;
            *(bf16x8*)&Vl[vd][((vjh * 4 + 2) ^ (vd & 7)) * 8] = vn2;
            *(bf16x8*)&Vl[vd][((vjh * 4 + 3) ^ (vd & 7)) * 8] = vn3;
            __syncthreads();
        }
    }

    // ---- fused LN1 epilogue (bf16 residual)
#pragma unroll
    for (int r = 0; r < 4; r++) {
        int il = iq * 16 + (lane >> 4) * 4 + r;
        size_t rowoff = ((size_t)(b * SS + i0 + il)) * 256 + dhalf * 128 + (lane & 15);
#pragma unroll
        for (int dq = 0; dq < 8; dq++)
            acc[dq][r] += (float)xinb[rowoff + dq * 16];
    }
    float sr[4], qr[4];
#pragma unroll
    for (int r = 0; r < 4; r++) {
        float s = 0.f, q = 0.f;
#pragma unroll
        for (int dq = 0; dq < 8; dq++) {
            float v = acc[dq][r];
            s += v; q += v * v;
        }
#pragma unroll
        for (int mask = 8; mask; mask >>= 1) {
            s += __shfl_xor(s, mask, 64);
            q += __shfl_xor(q, mask, 64);
        }
        sr[r] = s; qr[r] = q;
    }
    if ((lane & 15) == 0) {
#pragma unroll
        for (int r = 0; r < 4; r++) {
            int il = iq * 16 + (lane >> 4) * 4 + r;
            rowred[dhalf][il][0] = sr[r];
            rowred[dhalf][il][1] = qr[r];
        }
    }
    __syncthreads();
    float gv[8], bv2[8];
#pragma unroll
    for (int dq = 0; dq < 8; dq++) {
        int d = dhalf * 128 + dq * 16 + (lane & 15);
        gv[dq] = gamma[d];
        bv2[dq] = beta[d];
    }
#pragma unroll
    for (int r = 0; r < 4; r++) {
        int il = iq * 16 + (lane >> 4) * 4 + r;
        float st = rowred[0][il][0] + rowred[1][il][0];
        float qt = rowred[0][il][1] + rowred[1][il][1];
        float mean = st * (1.f / 256.f);
        float var = qt * (1.f / 256.f) - mean * mean;
        float inv = 1.f / sqrtf(var + LEPS);
        size_t rowoff = ((size_t)(b * SS + i0 + il)) * 256 + dhalf * 128 + (lane & 15);
#pragma unroll
        for (int dq = 0; dq < 8; dq++) {
            float o = (acc[dq][r] - mean) * inv * gv[dq] + bv2[dq];
            outb[rowoff + dq * 16] = (__bf16)o;
        }
    }
}

// ---------------- ff GEMM (BM=64, BN=256, 8 waves, grid 512) + fused LN2 (no affine)
__global__ __launch_bounds__(512) void gemm_ff_ln2(const __bf16* __restrict__ A,
                                                   const __bf16* __restrict__ WT,
                                                   const float* __restrict__ bias,
                                                   const __bf16* __restrict__ resid,
                                                   __bf16* __restrict__ outb) {
    const int t = threadIdx.x;
    const int w = t >> 6, lane = t & 63;
    const int m0 = blockIdx.x * 64;
    const int wr = (w >> 2) * 32, wc = (w & 3) * 64;
    __shared__ __align__(16) __bf16 Al[64][64];
    __shared__ __align__(16) __bf16 Wl[256][64];
    __shared__ float rowred[4][64][2];
    f32x4 acc[2][4] = {};

    for (int k0 = 0; k0 < 256; k0 += 64) {
        __syncthreads();
        {
            int r = t >> 3, c = t & 7;
            bf16x8 v = *(const bf16x8*)(A + (size_t)(m0 + r) * 256 + k0 + c * 8);
            *(bf16x8*)&Al[r][(c ^ (r & 7)) * 8] = v;
        }
        {
            int n = t >> 1, c0 = (t & 1) * 4;
            const __bf16* src = WT + (size_t)n * 256 + k0 + c0 * 8;
#pragma unroll
            for (int u = 0; u < 4; u++) {
                bf16x8 v = *(const bf16x8*)(src + u * 8);
                *(bf16x8*)&Wl[n][((c0 + u) ^ (n & 7)) * 8] = v;
            }
        }
        __syncthreads();
#pragma unroll
        for (int ks = 0; ks < 2; ks++) {
            int c = ks * 4 + (lane >> 4);
            bf16x8 af[2];
#pragma unroll
            for (int mf = 0; mf < 2; mf++) {
                int i = wr + mf * 16 + (lane & 15);
                af[mf] = *(const bf16x8*)&Al[i][(c ^ (i & 7)) * 8];
            }
#pragma unroll
            for (int nf = 0; nf < 4; nf++) {
                int n = wc + nf * 16 + (lane & 15);
                bf16x8 bfr = *(const bf16x8*)&Wl[n][(c ^ (n & 7)) * 8];
#pragma unroll
                for (int mf = 0; mf < 2; mf++)
                    acc[mf][nf] = __builtin_amdgcn_mfma_f32_16x16x32_bf16(af[mf], bfr, acc[mf][nf], 0, 0, 0);
            }
        }
    }
    float colb[4];
#pragma unroll
    for (int nf = 0; nf < 4; nf++) colb[nf] = bias[wc + nf * 16 + (lane & 15)];
#pragma unroll
    for (int mf = 0; mf < 2; mf++) {
#pragma unroll
        for (int r = 0; r < 4; r++) {
            int rl = wr + mf * 16 + (lane >> 4) * 4 + r;
            const __bf16* rrow = resid + (size_t)(m0 + rl) * 256 + wc + (lane & 15);
            float s = 0.f, q = 0.f;
#pragma unroll
            for (int nf = 0; nf < 4; nf++) {
                float v = fmaxf(acc[mf][nf][r] + colb[nf], 0.f) + (float)rrow[nf * 16];
                acc[mf][nf][r] = v;
                s += v; q += v * v;
            }
#pragma unroll
            for (int msk = 1; msk <= 8; msk <<= 1) {
                s += __shfl_xor(s, msk, 64);
                q += __shfl_xor(q, msk, 64);
            }
            if ((lane & 15) == 0) {
                rowred[w & 3][rl][0] = s;
                rowred[w & 3][rl][1] = q;
            }
        }
    }
    __syncthreads();
#pragma unroll
    for (int mf = 0; mf < 2; mf++) {
#pragma unroll
        for (int r = 0; r < 4; r++) {
            int rl = wr + mf * 16 + (lane >> 4) * 4 + r;
            float s = rowred[0][rl][0] + rowred[1][rl][0] + rowred[2][rl][0] + rowred[3][rl][0];
            float q = rowred[0][rl][1] + rowred[1][rl][1] + rowred[2][rl][1] + rowred[3][rl][1];
            float mean = s * (1.f / 256.f);
            float var = q * (1.f / 256.f) - mean * mean;
            float inv = 1.f / sqrtf(var + LEPS);
            size_t base = (size_t)(m0 + rl) * 256 + wc + (lane & 15);
#pragma unroll
            for (int nf = 0; nf < 4; nf++) {
                float o = (acc[mf][nf][r] - mean) * inv;
                outb[base + nf * 16] = (__bf16)o;
            }
        }
    }
}

// ---------------- pooling P1: per-(b,h) softmax -> normalized weights
__global__ __launch_bounds__(256) void pool_softmax(const float* __restrict__ pk,
                                                    const float* __restrict__ queries,
                                                    float* __restrict__ wout) {
    const int b = blockIdx.x, h = blockIdx.y;
    const int t = threadIdx.x;
    const int wv = t >> 6, lane = t & 63;
    __shared__ float qv[16];
    __shared__ float redm[4], reds[4];
    if (t < 16) qv[t] = queries[h * 16 + t];
    __syncthreads();
    float sc[4];
#pragma unroll
    for (int c = 0; c < 4; c++) {
        int s = c * 256 + t;
        const float* p = pk + ((size_t)b * SS + s) * 16;
        float4 a0 = *(const float4*)p;
        float4 a1 = *(const float4*)(p + 4);
        float4 a2 = *(const float4*)(p + 8);
        float4 a3 = *(const float4*)(p + 12);
        sc[c] = a0.x * qv[0] + a0.y * qv[1] + a0.z * qv[2] + a0.w * qv[3]
              + a1.x * qv[4] + a1.y * qv[5] + a1.z * qv[6] + a1.w * qv[7]
              + a2.x * qv[8] + a2.y * qv[9] + a2.z * qv[10] + a2.w * qv[11]
              + a3.x * qv[12] + a3.y * qv[13] + a3.z * qv[14] + a3.w * qv[15];
    }
    float m = fmaxf(fmaxf(sc[0], sc[1]), fmaxf(sc[2], sc[3]));
    for (int off = 32; off; off >>= 1) m = fmaxf(m, __shfl_xor(m, off, 64));
    if (lane == 0) redm[wv] = m;
    __syncthreads();
    m = fmaxf(fmaxf(redm[0], redm[1]), fmaxf(redm[2], redm[3]));
    float e[4];
    float sum = 0.f;
#pragma unroll
    for (int c = 0; c < 4; c++) { e[c] = expf(sc[c] - m); sum += e[c]; }
    for (int off = 32; off; off >>= 1) sum += __shfl_xor(sum, off, 64);
    if (lane == 0) reds[wv] = sum;
    __syncthreads();
    float inv = 1.f / (reds[0] + reds[1] + reds[2] + reds[3]);
#pragma unroll
    for (int c = 0; c < 4; c++)
        wout[((size_t)(b * 4 + h)) * SS + c * 256 + t] = e[c] * inv;
}

// ---------------- pooling P2: partial weighted sums over s-chunks of 64
__global__ __launch_bounds__(256) void pool_wsum(const float* __restrict__ wgt,
                                                 const float* __restrict__ pv,
                                                 float* __restrict__ partial) {
    const int b = blockIdx.x, c = blockIdx.y;
    const int h = threadIdx.x >> 6, d = threadIdx.x & 63;
    const float* wrow = wgt + ((size_t)(b * 4 + h)) * SS + c * 64;
    const float* pvb = pv + ((size_t)(b * SS + c * 64)) * 64 + d;
    float a = 0.f;
#pragma unroll 8
    for (int s = 0; s < 64; s++) a += wrow[s] * pvb[(size_t)s * 64];
    partial[((size_t)b * 16 + c) * 256 + threadIdx.x] = a;
}

// ---------------- pooling P3: reduce partials + final linear
__global__ __launch_bounds__(256) void pool_final(const float* __restrict__ partial,
                                                  const float* __restrict__ W1,
                                                  const float* __restrict__ b1,
                                                  float* __restrict__ out) {
    const int b = blockIdx.x, t = threadIdx.x;
    __shared__ float r0[256], r1[256];
    float a = 0.f;
#pragma unroll
    for (int c = 0; c < 16; c++) a += partial[((size_t)b * 16 + c) * 256 + t];
    r0[t] = a * W1[t * 2 + 0];
    r1[t] = a * W1[t * 2 + 1];
    __syncthreads();
    for (int off = 128; off > 0; off >>= 1) {
        if (t < off) { r0[t] += r0[t + off]; r1[t] += r1[t + off]; }
        __syncthreads();
    }
    if (t == 0) {
        out[b * 2 + 0] = r0[0] + b1[0];
        out[b * 2 + 1] = r1[0] + b1[1];
    }
}

extern "C" void kernel_launch(void* const* d_in, const int* in_sizes, int n_in,
                              void* d_out, int out_size, void* d_ws, size_t ws_size,
                              hipStream_t stream) {
    const float* input = (const float*)d_in[0];
    const float* eWk = (const float*)d_in[3];
    const float* ebk = (const float*)d_in[4];
    const float* eWq = (const float*)d_in[5];
    const float* ebq = (const float*)d_in[6];
    const float* eWv = (const float*)d_in[7];
    const float* ebv = (const float*)d_in[8];
    const float* eWb = (const float*)d_in[9];
    const float* ebb = (const float*)d_in[10];
    const float* eWff = (const float*)d_in[11];
    const float* ebff = (const float*)d_in[12];
    const float* eg1 = (const float*)d_in[13];
    const float* ebe1 = (const float*)d_in[14];
    const float* pWk = (const float*)d_in[15];
    const float* pbk = (const float*)d_in[16];
    const float* pWv = (const float*)d_in[17];
    const float* pbv = (const float*)d_in[18];
    const float* qrs = (const float*)d_in[19];
    const float* W1 = (const float*)d_in[20];
    const float* b1 = (const float*)d_in[21];
    float* out = (float*)d_out;

    // ---- workspace layout (bf16-only inter-kernel dataflow)
    float* ws = (float*)d_ws;
    float* xbuf = ws;                               // (reserved)
    __bf16* xbf = (__bf16*)(xbuf + (size_t)MM * DD);      // MM*256 bf16 — THE x
    float* tmp2 = (float*)(xbf + (size_t)MM * DD);        // tail scratch
    float* r3 = tmp2 + (size_t)MM * DD;
    __bf16* tmp2bf = (__bf16*)r3;                   //   LN1 bf16 (attn epilogue)
    __bf16* vTb = tmp2bf + (size_t)MM * DD;         //   vT [B][256][1024]
    float* r4 = r3 + (size_t)MM * DD;
    __bf16* kbf = (__bf16*)r4;                      //   k bf16
    __bf16* qbf = kbf + (size_t)MM * 64;            //   q bf16
    float* bbuf = r4 + (size_t)MM * (DD / 2);       // MM f32
    __bf16* wbf = (__bf16*)(bbuf + MM);             // weights bf16

    __bf16* WkqT = wbf;                     // [4][128][256]
    __bf16* WvT = WkqT + 4 * 128 * 256;     // [4][256][256]
    __bf16* WffT = WvT + 4 * 256 * 256;     // [4][256][256]
    __bf16* pWkT = WffT + 4 * 256 * 256;    // [16][256], pre-scaled
    __bf16* pWvT = pWkT + 16 * 256;         // [64][256]
    float* biasc = (float*)(pWvT + 64 * 256);  // [4][128]

    // tail-phase buffers inside tmp2 region
    float* pkbuf = tmp2;                        // MM*16
    float* pvbuf = tmp2 + (size_t)MM * 16;      // MM*64
    float* wgtbuf = tmp2 + (size_t)MM * 80;     // 32*4*1024
    float* partial = wgtbuf + (size_t)BB * 4 * SS;  // 32*16*256

    const float SC = 0.125f;  // 1/sqrt(64)

    cast_wt<<<dim3(64, 1, 4), 256, 0, stream>>>(eWk, WkqT, 64, SC, 128 * 256, 0);
    cast_wt<<<dim3(64, 1, 4), 256, 0, stream>>>(eWq, WkqT, 64, 1.f, 128 * 256, 64);
    cast_wt<<<dim3(256, 1, 4), 256, 0, stream>>>(eWv, WvT, 256, 1.f, 256 * 256, 0);
    cast_wt<<<dim3(256, 1, 4), 256, 0, stream>>>(eWff, WffT, 256, 1.f, 256 * 256, 0);
    cast_wt<<<dim3(16, 1, 1), 256, 0, stream>>>(pWk, pWkT, 16, SC, 16 * 256, 0);
    cast_wt<<<dim3(64, 1, 1), 256, 0, stream>>>(pWv, pWvT, 64, 1.f, 64 * 256, 0);
    bias_combine<<<4, 128, 0, stream>>>(ebk, ebq, biasc);
    cast_x<<<MM * DD / (256 * 8), 256, 0, stream>>>(input, xbf);

    for (int l = 0; l < 4; l++) {
        gemm_kq_vt<<<dim3(768, 1), 256, 0, stream>>>(
            xbf, WkqT + (size_t)l * 128 * 256, biasc + l * 128, kbf, qbf,
            WvT + (size_t)l * 256 * 256, ebv + l * DD, vTb);
        bias_gemv<<<MM / 4, 256, 0, stream>>>(xbf, eWb + (size_t)l * DD, ebb + l, bbuf);
        attn_mfma<<<dim3(512, 1), 512, 0, stream>>>(kbf, qbf, vTb, bbuf, xbf,
                                                    eg1 + l * DD, ebe1 + l * DD, tmp2bf);
        gemm_ff_ln2<<<dim3(MM / 64, 1), 512, 0, stream>>>(
            tmp2bf, WffT + (size_t)l * 256 * 256, ebff + l * DD, tmp2bf, xbf);
    }
    gemm_mfma<16, 0><<<dim3(MM / 128, 1), 256, 0, stream>>>(xbf, pWkT, pbk, SC, 0, pkbuf, nullptr, 16);
    gemm_mfma<64, 0><<<dim3(MM / 128, 1), 256, 0, stream>>>(xbf, pWvT, pbv, 1.f, 0, pvbuf, nullptr, 64);
    pool_softmax<<<dim3(BB, 4), 256, 0, stream>>>(pkbuf, qrs, wgtbuf);
    pool_wsum<<<dim3(BB, 16), 256, 0, stream>>>(wgtbuf, pvbuf, partial);
    pool_final<<<BB, 256, 0, stream>>>(partial, W1, b1, out);
}

// Round 17
// 403.122 us; speedup vs baseline: 1.1178x; 1.0376x over previous
//
#include <hip/hip_runtime.h>
#include <hip/hip_bf16.h>
#include <math.h>

#define BB 32
#define SS 1024
#define DD 256
#define MM (BB*SS)   // 32768
#define LEPS 1e-5f

typedef __bf16 bf16x8 __attribute__((ext_vector_type(8)));
typedef __bf16 bf16x4 __attribute__((ext_vector_type(4)));
typedef float f32x4 __attribute__((ext_vector_type(4)));

// ---------------- weight cast+transpose: dst[l*dstride + (n+noff)*256 + k] = W[l][k][n]*scale
__global__ __launch_bounds__(256) void cast_wt(const float* __restrict__ W,
                                               __bf16* __restrict__ WT,
                                               int N, float scale, int dstride, int noff) {
    int n = blockIdx.x, l = blockIdx.z, k = threadIdx.x;
    WT[(size_t)dstride * l + (size_t)(n + noff) * 256 + k] =
        (__bf16)(W[(size_t)256 * N * l + (size_t)k * N + n] * scale);
}

// ---------------- combined k/q bias: dst[l][j] = j<64 ? bk*SC : bq
__global__ __launch_bounds__(128) void bias_combine(const float* __restrict__ bk,
                                                    const float* __restrict__ bq,
                                                    float* __restrict__ dst) {
    int l = blockIdx.x, j = threadIdx.x;
    dst[l * 128 + j] = (j < 64) ? bk[l * 64 + j] * 0.125f : bq[l * 64 + (j - 64)];
}

// ---------------- cast fp32 -> bf16, 8 elems/thread
__global__ __launch_bounds__(256) void cast_x(const float* __restrict__ x, __bf16* __restrict__ xb) {
    size_t i = ((size_t)blockIdx.x * 256 + threadIdx.x) * 8;
    float4 a = *(const float4*)(x + i);
    float4 b = *(const float4*)(x + i + 4);
    __bf16 o[8] __attribute__((aligned(16)));
    o[0] = (__bf16)a.x; o[1] = (__bf16)a.y; o[2] = (__bf16)a.z; o[3] = (__bf16)a.w;
    o[4] = (__bf16)b.x; o[5] = (__bf16)b.y; o[6] = (__bf16)b.z; o[7] = (__bf16)b.w;
    *(bf16x8*)(xb + i) = *(bf16x8*)o;
}

// ---------------- fused per-layer kq-GEMM + bias-GEMV + vT-producer (768 blocks, 256 thr)
// blocks [0,256): kq:  C = x @ WkqT^T + biasc, split to kq0/kq1; bias[row] = x[row,:].Wb + bb0
// blocks [256,768): vT: vT[b][d][s] = WvT[d,:] . x[b,s,:] + bv[d], LDS-bounce stores
__global__ __launch_bounds__(256) void gemm_kq_vt(const __bf16* __restrict__ xbf,
                                                  const __bf16* __restrict__ WkqT,
                                                  const float* __restrict__ biasc,
                                                  __bf16* __restrict__ kq0,
                                                  __bf16* __restrict__ kq1,
                                                  const __bf16* __restrict__ WvT,
                                                  const float* __restrict__ bv,
                                                  __bf16* __restrict__ vTb,
                                                  const float* __restrict__ Wb,
                                                  const float* __restrict__ bb0,
                                                  float* __restrict__ bbuf_out) {
    const int t = threadIdx.x;
    const int w = t >> 6, lane = t & 63;
    const int wr = (w >> 1) * 64;
    const int wc = (w & 1) * 64;
    __shared__ __align__(16) __bf16 smem[128 * 64 + 128 * 64];
    __bf16 (*Al)[64] = (__bf16(*)[64])smem;
    __bf16 (*Wl)[64] = (__bf16(*)[64])(smem + 128 * 64);
    f32x4 acc[4][4] = {};

    const bool is_kq = (blockIdx.x < 256);
    const __bf16* A;
    const __bf16* WT;
    size_t wt_z = 0, c_z = 0;
    int m0, n0;
    if (is_kq) {
        A = xbf; WT = WkqT;
        m0 = blockIdx.x * 128; n0 = 0;
    } else {
        int v = blockIdx.x - 256;
        int bxv = v & 1, by = (v >> 1) & 7, bz = v >> 4;
        A = WvT; WT = xbf;
        m0 = bxv * 128; n0 = by * 128;
        wt_z = (size_t)bz * SS * 256;
        c_z = (size_t)bz * 256 * (size_t)SS;
    }

    float pb = 0.f;  // bias-GEMV partial (kq path only)

    for (int k0 = 0; k0 < 256; k0 += 64) {
        __syncthreads();
        {
            int r = t >> 1, half = t & 1;
            const __bf16* src = A + (size_t)(m0 + r) * 256 + k0 + half * 32;
            bf16x8 v0 = *(const bf16x8*)(src);
            bf16x8 v1 = *(const bf16x8*)(src + 8);
            bf16x8 v2 = *(const bf16x8*)(src + 16);
            bf16x8 v3 = *(const bf16x8*)(src + 24);
            int cb = half * 4;
            *(bf16x8*)&Al[r][((cb + 0) ^ (r & 7)) * 8] = v0;
            *(bf16x8*)&Al[r][((cb + 1) ^ (r & 7)) * 8] = v1;
            *(bf16x8*)&Al[r][((cb + 2) ^ (r & 7)) * 8] = v2;
            *(bf16x8*)&Al[r][((cb + 3) ^ (r & 7)) * 8] = v3;
            if (is_kq) {   // ride-along bias GEMV: x rows are in registers right now
                const float* wbp = Wb + k0 + half * 32;
#pragma unroll
                for (int e = 0; e < 8; e++) {
                    pb += (float)v0[e] * wbp[e];
                    pb += (float)v1[e] * wbp[8 + e];
                    pb += (float)v2[e] * wbp[16 + e];
                    pb += (float)v3[e] * wbp[24 + e];
                }
            }
        }
        {
            int r = t >> 1, half = t & 1;
            const __bf16* src = WT + wt_z + (size_t)(n0 + r) * 256 + k0 + half * 32;
            bf16x8 v0 = *(const bf16x8*)(src);
            bf16x8 v1 = *(const bf16x8*)(src + 8);
            bf16x8 v2 = *(const bf16x8*)(src + 16);
            bf16x8 v3 = *(const bf16x8*)(src + 24);
            int cb = half * 4;
            *(bf16x8*)&Wl[r][((cb + 0) ^ (r & 7)) * 8] = v0;
            *(bf16x8*)&Wl[r][((cb + 1) ^ (r & 7)) * 8] = v1;
            *(bf16x8*)&Wl[r][((cb + 2) ^ (r & 7)) * 8] = v2;
            *(bf16x8*)&Wl[r][((cb + 3) ^ (r & 7)) * 8] = v3;
        }
        __syncthreads();
#pragma unroll
        for (int ks = 0; ks < 2; ks++) {
            int c = ks * 4 + (lane >> 4);
            bf16x8 af[4];
#pragma unroll
            for (int mf = 0; mf < 4; mf++) {
                int i = wr + mf * 16 + (lane & 15);
                af[mf] = *(const bf16x8*)&Al[i][(c ^ (i & 7)) * 8];
            }
#pragma unroll
            for (int nf = 0; nf < 4; nf++) {
                int n = wc + nf * 16 + (lane & 15);
                bf16x8 bfr = *(const bf16x8*)&Wl[n][(c ^ (n & 7)) * 8];
#pragma unroll
                for (int mf = 0; mf < 4; mf++)
                    acc[mf][nf] = __builtin_amdgcn_mfma_f32_16x16x32_bf16(af[mf], bfr, acc[mf][nf], 0, 0, 0);
            }
        }
    }
    if (is_kq) {
        // finish bias GEMV: combine halves (threads t, t^1 share a row)
        float s = pb + __shfl_xor(pb, 1, 64);
        if ((t & 1) == 0) bbuf_out[m0 + (t >> 1)] = s + bb0[0];
        // kq split epilogue
#pragma unroll
        for (int mf = 0; mf < 4; mf++) {
#pragma unroll
            for (int nf = 0; nf < 4; nf++) {
                int col = wc + nf * 16 + (lane & 15);
                float bcol = biasc[col];
#pragma unroll
                for (int r = 0; r < 4; r++) {
                    int row = m0 + wr + mf * 16 + (lane >> 4) * 4 + r;
                    float v = acc[mf][nf][r] + bcol;
                    if (col < 64) kq0[(size_t)row * 64 + col] = (__bf16)v;
                    else kq1[(size_t)row * 64 + (col - 64)] = (__bf16)v;
                }
            }
        }
    } else {
        // vT LDS-bounce epilogue
        __syncthreads();
#pragma unroll
        for (int mf = 0; mf < 4; mf++) {
#pragma unroll
            for (int nf = 0; nf < 4; nf++) {
                int col = wc + nf * 16 + (lane & 15);
#pragma unroll
                for (int r = 0; r < 4; r++) {
                    int row = wr + mf * 16 + (lane >> 4) * 4 + r;
                    float v = acc[mf][nf][r] + bv[m0 + row];
                    smem[row * 128 + (((col >> 3) ^ (row & 15)) * 8) + (col & 7)] = (__bf16)v;
                }
            }
        }
        __syncthreads();
#pragma unroll
        for (int p = 0; p < 2; p++) {
            int row = p * 64 + (t >> 2);
            int cq = (t & 3) * 4;
            __bf16* dst = vTb + c_z + (size_t)(m0 + row) * SS + n0 + (t & 3) * 32;
#pragma unroll
            for (int u = 0; u < 4; u++) {
                int ch = (cq + u) ^ (row & 15);
                *(bf16x8*)(dst + u * 8) = *(const bf16x8*)&smem[row * 128 + ch * 8];
            }
        }
    }
}

// ---------------- MFMA GEMM (tail only): C = A[M,256] @ WT[N,256]^T + bias
template <int BN, int MODE>
__global__ __launch_bounds__(256) void gemm_mfma(const __bf16* __restrict__ A,
                                                 const __bf16* __restrict__ WT,
                                                 const float* __restrict__ bias,
                                                 float bscale, int relu,
                                                 void* __restrict__ Cv, void* __restrict__ Cv2,
                                                 int N) {
    constexpr int MR = (BN == 128) ? 4 : 2;
    constexpr int NC = (BN == 128) ? 4 : BN / 16;
    const int t = threadIdx.x;
    const int w = t >> 6, lane = t & 63;
    const int m0 = blockIdx.x * 128;
    const int n0 = blockIdx.y * BN;
    const int wr = (BN == 128) ? (w >> 1) * 64 : w * 32;
    const int wc = (BN == 128) ? (w & 1) * 64 : 0;
    __shared__ __align__(16) __bf16 smem[128 * 64 + BN * 64];
    __bf16 (*Al)[64] = (__bf16(*)[64])smem;
    __bf16 (*Wl)[64] = (__bf16(*)[64])(smem + 128 * 64);
    f32x4 acc[MR][NC] = {};

    for (int k0 = 0; k0 < 256; k0 += 64) {
        __syncthreads();
        {
            int r = t >> 1, half = t & 1;
            const __bf16* src = A + (size_t)(m0 + r) * 256 + k0 + half * 32;
            bf16x8 v0 = *(const bf16x8*)(src);
            bf16x8 v1 = *(const bf16x8*)(src + 8);
            bf16x8 v2 = *(const bf16x8*)(src + 16);
            bf16x8 v3 = *(const bf16x8*)(src + 24);
            int cb = half * 4;
            *(bf16x8*)&Al[r][((cb + 0) ^ (r & 7)) * 8] = v0;
            *(bf16x8*)&Al[r][((cb + 1) ^ (r & 7)) * 8] = v1;
            *(bf16x8*)&Al[r][((cb + 2) ^ (r & 7)) * 8] = v2;
            *(bf16x8*)&Al[r][((cb + 3) ^ (r & 7)) * 8] = v3;
        }
        if (BN == 64) {
            int n = t >> 2, q = t & 3;
            const __bf16* src = WT + (size_t)(n0 + n) * 256 + k0 + q * 16;
            bf16x8 v0 = *(const bf16x8*)src;
            bf16x8 v1 = *(const bf16x8*)(src + 8);
            *(bf16x8*)&Wl[n][((q * 2 + 0) ^ (n & 7)) * 8] = v0;
            *(bf16x8*)&Wl[n][((q * 2 + 1) ^ (n & 7)) * 8] = v1;
        } else {
            if (t < 128) {
                int n = t >> 3, c = t & 7;
                bf16x8 v = *(const bf16x8*)(WT + (size_t)(n0 + n) * 256 + k0 + c * 8);
                *(bf16x8*)&Wl[n][(c ^ (n & 7)) * 8] = v;
            }
        }
        __syncthreads();
#pragma unroll
        for (int ks = 0; ks < 2; ks++) {
            int c = ks * 4 + (lane >> 4);
            bf16x8 af[MR];
#pragma unroll
            for (int mf = 0; mf < MR; mf++) {
                int i = wr + mf * 16 + (lane & 15);
                af[mf] = *(const bf16x8*)&Al[i][(c ^ (i & 7)) * 8];
            }
#pragma unroll
            for (int nf = 0; nf < NC; nf++) {
                int n = wc + nf * 16 + (lane & 15);
                bf16x8 bfr = *(const bf16x8*)&Wl[n][(c ^ (n & 7)) * 8];
#pragma unroll
                for (int mf = 0; mf < MR; mf++)
                    acc[mf][nf] = __builtin_amdgcn_mfma_f32_16x16x32_bf16(af[mf], bfr, acc[mf][nf], 0, 0, 0);
            }
        }
    }
#pragma unroll
    for (int mf = 0; mf < MR; mf++) {
#pragma unroll
        for (int nf = 0; nf < NC; nf++) {
            int col = n0 + wc + nf * 16 + (lane & 15);
            float bcol = bias[col] * bscale;
#pragma unroll
            for (int r = 0; r < 4; r++) {
                int row = m0 + wr + mf * 16 + (lane >> 4) * 4 + r;
                float v = acc[mf][nf][r] + bcol;
                if (relu) v = fmaxf(v, 0.f);
                ((float*)Cv)[(size_t)row * N + col] = v;
            }
        }
    }
}

// ---------------- MFMA fused attention + LN1 (8 waves, j-tile 64, 16x16 MFMA)
// R13-proven version (best measured): Kl/bsh in LDS, T14 async-stage + setprio, bf16 dataflow.
__global__ __launch_bounds__(512, 4) void attn_mfma(const __bf16* __restrict__ kb,
                                                    const __bf16* __restrict__ qb,
                                                    const __bf16* __restrict__ vT,
                                                    const float* __restrict__ biasb,
                                                    const __bf16* __restrict__ xinb,
                                                    const float* __restrict__ gamma,
                                                    const float* __restrict__ beta,
                                                    __bf16* __restrict__ outb) {
    int h = blockIdx.x;
    int blow = h & 7, rest = h >> 3;
    int ib = rest & 15;
    int b = blow + (rest >> 4) * 8;
    const int i0 = ib * 64;
    const int t = threadIdx.x;
    const int w = t >> 6, lane = t & 63;
    const int iq = w >> 1;
    const int dhalf = w & 1;

    __shared__ __align__(16) __bf16 Kl[64][64];
    __shared__ __align__(16) __bf16 Ql[64][64];
    __shared__ __align__(16) __bf16 Vl[256][64];
    __shared__ __align__(16) __bf16 Sl[64][64];
    __shared__ float bsh[64];
    __shared__ float rowred[2][64][2];

    const int qj = t >> 3, qc = t & 7;
    const __bf16* qsrc_base = qb + ((size_t)(b * SS + qj)) * 64 + qc * 8;
    const int vd = t >> 1, vjh = t & 1;
    const __bf16* vsrc_base = vT + ((size_t)b * 256 + vd) * SS + vjh * 32;

    {   // stage K once + bias
        int i = t >> 3, c = t & 7;
        bf16x8 v = *(const bf16x8*)(kb + ((size_t)(b * SS + i0 + i)) * 64 + c * 8);
        *(bf16x8*)&Kl[i][(c ^ (i & 7)) * 8] = v;
        if (t < 64) bsh[t] = biasb[b * SS + i0 + t];
    }
    {   // prologue: stage Q/V for j0=0
        bf16x8 qv = *(const bf16x8*)(qsrc_base);
        *(bf16x8*)&Ql[qj][(qc ^ (qj & 7)) * 8] = qv;
#pragma unroll
        for (int u = 0; u < 4; u++) {
            bf16x8 v = *(const bf16x8*)(vsrc_base + u * 8);
            *(bf16x8*)&Vl[vd][((vjh * 4 + u) ^ (vd & 7)) * 8] = v;
        }
    }
    __syncthreads();

    f32x4 acc[8] = {};

    for (int j0 = 0; j0 < SS; j0 += 64) {
        const bool has_next = (j0 + 64) < SS;
        bf16x8 qn;
        bf16x8 vn0, vn1, vn2, vn3;
        if (has_next) {
            qn = *(const bf16x8*)(qsrc_base + (size_t)(j0 + 64) * 64);
            const __bf16* vs = vsrc_base + j0 + 64;
            vn0 = *(const bf16x8*)(vs);
            vn1 = *(const bf16x8*)(vs + 8);
            vn2 = *(const bf16x8*)(vs + 16);
            vn3 = *(const bf16x8*)(vs + 24);
        }
        // ---- S phase
#pragma unroll
        for (int jj = 0; jj < 2; jj++) {
            int jq = (w & 1) * 2 + jj;
            f32x4 sacc = {0.f, 0.f, 0.f, 0.f};
            __builtin_amdgcn_s_setprio(1);
#pragma unroll
            for (int ks = 0; ks < 2; ks++) {
                int i = iq * 16 + (lane & 15);
                int ck = ks * 4 + (lane >> 4);
                bf16x8 a = *(const bf16x8*)&Kl[i][(ck ^ (i & 7)) * 8];
                int j = jq * 16 + (lane & 15);
                bf16x8 bq = *(const bf16x8*)&Ql[j][(ck ^ (j & 7)) * 8];
                sacc = __builtin_amdgcn_mfma_f32_16x16x32_bf16(a, bq, sacc, 0, 0, 0);
            }
            __builtin_amdgcn_s_setprio(0);
            int jcol = jq * 16 + (lane & 15);
#pragma unroll
            for (int r = 0; r < 4; r++) {
                int irow = iq * 16 + (lane >> 4) * 4 + r;
                float x = sacc[r] + bsh[irow];
                float sg = 1.f / (1.f + __expf(-x));
                Sl[irow][(((jcol >> 3) ^ (irow & 7)) * 8) + (jcol & 7)] = (__bf16)sg;
            }
        }
        __syncthreads();
        // ---- PV phase
        bf16x8 am[2];
#pragma unroll
        for (int m = 0; m < 2; m++) {
            int i = iq * 16 + (lane & 15);
            int cj = m * 4 + (lane >> 4);
            am[m] = *(const bf16x8*)&Sl[i][(cj ^ (i & 7)) * 8];
        }
        __builtin_amdgcn_s_setprio(1);
#pragma unroll
        for (int dq = 0; dq < 8; dq++) {
            int d = dhalf * 128 + dq * 16 + (lane & 15);
#pragma unroll
            for (int m = 0; m < 2; m++) {
                int cj = m * 4 + (lane >> 4);
                bf16x8 bv = *(const bf16x8*)&Vl[d][(cj ^ (d & 7)) * 8];
                acc[dq] = __builtin_amdgcn_mfma_f32_16x16x32_bf16(am[m], bv, acc[dq], 0, 0, 0);
            }
        }
        __builtin_amdgcn_s_setprio(0);
        __syncthreads();
        if (has_next) {
            *(bf16x8*)&Ql[qj][(qc ^ (qj & 7)) * 8] = qn;
            *(bf16x8*)&Vl[vd][((vjh * 4 + 0) ^ (vd & 7)) * 8] = vn0;
            *(bf16x8*)&Vl[vd][((vjh * 4 + 1) ^ (vd & 7)) * 8] = vn1;
            *(bf16x8*)&Vl[vd][((vjh * 4 + 2) ^ (vd & 7)) * 8] = vn2;
            *(bf16x8*)&Vl[vd][((vjh * 4 + 3) ^ (vd & 7)) * 8] = vn3;
            __syncthreads();
        }
    }

    // ---- fused LN1 epilogue (bf16 residual)
#pragma unroll
    for (int r = 0; r < 4; r++) {
        int il = iq * 16 + (lane >> 4) * 4 + r;
        size_t rowoff = ((size_t)(b * SS + i0 + il)) * 256 + dhalf * 128 + (lane & 15);
#pragma unroll
        for (int dq = 0; dq < 8; dq++)
            acc[dq][r] += (float)xinb[rowoff + dq * 16];
    }
    float sr[4], qr[4];
#pragma unroll
    for (int r = 0; r < 4; r++) {
        float s = 0.f, q = 0.f;
#pragma unroll
        for (int dq = 0; dq < 8; dq++) {
            float v = acc[dq][r];
            s += v; q += v * v;
        }
#pragma unroll
        for (int mask = 8; mask; mask >>= 1) {
            s += __shfl_xor(s, mask, 64);
            q += __shfl_xor(q, mask, 64);
        }
        sr[r] = s; qr[r] = q;
    }
    if ((lane & 15) == 0) {
#pragma unroll
        for (int r = 0; r < 4; r++) {
            int il = iq * 16 + (lane >> 4) * 4 + r;
            rowred[dhalf][il][0] = sr[r];
            rowred[dhalf][il][1] = qr[r];
        }
    }
    __syncthreads();
    float gv[8], bv2[8];
#pragma unroll
    for (int dq = 0; dq < 8; dq++) {
        int d = dhalf * 128 + dq * 16 + (lane & 15);
        gv[dq] = gamma[d];
        bv2[dq] = beta[d];
    }
#pragma unroll
    for (int r = 0; r < 4; r++) {
        int il = iq * 16 + (lane >> 4) * 4 + r;
        float st = rowred[0][il][0] + rowred[1][il][0];
        float qt = rowred[0][il][1] + rowred[1][il][1];
        float mean = st * (1.f / 256.f);
        float var = qt * (1.f / 256.f) - mean * mean;
        float inv = 1.f / sqrtf(var + LEPS);
        size_t rowoff = ((size_t)(b * SS + i0 + il)) * 256 + dhalf * 128 + (lane & 15);
#pragma unroll
        for (int dq = 0; dq < 8; dq++) {
            float o = (acc[dq][r] - mean) * inv * gv[dq] + bv2[dq];
            outb[rowoff + dq * 16] = (__bf16)o;
        }
    }
}

// ---------------- ff GEMM (BM=64, BN=256, 8 waves, grid 512) + fused LN2 (no affine)
__global__ __launch_bounds__(512) void gemm_ff_ln2(const __bf16* __restrict__ A,
                                                   const __bf16* __restrict__ WT,
                                                   const float* __restrict__ bias,
                                                   const __bf16* __restrict__ resid,
                                                   __bf16* __restrict__ outb) {
    const int t = threadIdx.x;
    const int w = t >> 6, lane = t & 63;
    const int m0 = blockIdx.x * 64;
    const int wr = (w >> 2) * 32, wc = (w & 3) * 64;
    __shared__ __align__(16) __bf16 Al[64][64];
    __shared__ __align__(16) __bf16 Wl[256][64];
    __shared__ float rowred[4][64][2];
    f32x4 acc[2][4] = {};

    for (int k0 = 0; k0 < 256; k0 += 64) {
        __syncthreads();
        {
            int r = t >> 3, c = t & 7;
            bf16x8 v = *(const bf16x8*)(A + (size_t)(m0 + r) * 256 + k0 + c * 8);
            *(bf16x8*)&Al[r][(c ^ (r & 7)) * 8] = v;
        }
        {
            int n = t >> 1, c0 = (t & 1) * 4;
            const __bf16* src = WT + (size_t)n * 256 + k0 + c0 * 8;
#pragma unroll
            for (int u = 0; u < 4; u++) {
                bf16x8 v = *(const bf16x8*)(src + u * 8);
                *(bf16x8*)&Wl[n][((c0 + u) ^ (n & 7)) * 8] = v;
            }
        }
        __syncthreads();
#pragma unroll
        for (int ks = 0; ks < 2; ks++) {
            int c = ks * 4 + (lane >> 4);
            bf16x8 af[2];
#pragma unroll
            for (int mf = 0; mf < 2; mf++) {
                int i = wr + mf * 16 + (lane & 15);
                af[mf] = *(const bf16x8*)&Al[i][(c ^ (i & 7)) * 8];
            }
#pragma unroll
            for (int nf = 0; nf < 4; nf++) {
                int n = wc + nf * 16 + (lane & 15);
                bf16x8 bfr = *(const bf16x8*)&Wl[n][(c ^ (n & 7)) * 8];
#pragma unroll
                for (int mf = 0; mf < 2; mf++)
                    acc[mf][nf] = __builtin_amdgcn_mfma_f32_16x16x32_bf16(af[mf], bfr, acc[mf][nf], 0, 0, 0);
            }
        }
    }
    float colb[4];
#pragma unroll
    for (int nf = 0; nf < 4; nf++) colb[nf] = bias[wc + nf * 16 + (lane & 15)];
#pragma unroll
    for (int mf = 0; mf < 2; mf++) {
#pragma unroll
        for (int r = 0; r < 4; r++) {
            int rl = wr + mf * 16 + (lane >> 4) * 4 + r;
            const __bf16* rrow = resid + (size_t)(m0 + rl) * 256 + wc + (lane & 15);
            float s = 0.f, q = 0.f;
#pragma unroll
            for (int nf = 0; nf < 4; nf++) {
                float v = fmaxf(acc[mf][nf][r] + colb[nf], 0.f) + (float)rrow[nf * 16];
                acc[mf][nf][r] = v;
                s += v; q += v * v;
            }
#pragma unroll
            for (int msk = 1; msk <= 8; msk <<= 1) {
                s += __shfl_xor(s, msk, 64);
                q += __shfl_xor(q, msk, 64);
            }
            if ((lane & 15) == 0) {
                rowred[w & 3][rl][0] = s;
                rowred[w & 3][rl][1] = q;
            }
        }
    }
    __syncthreads();
#pragma unroll
    for (int mf = 0; mf < 2; mf++) {
#pragma unroll
        for (int r = 0; r < 4; r++) {
            int rl = wr + mf * 16 + (lane >> 4) * 4 + r;
            float s = rowred[0][rl][0] + rowred[1][rl][0] + rowred[2][rl][0] + rowred[3][rl][0];
            float q = rowred[0][rl][1] + rowred[1][rl][1] + rowred[2][rl][1] + rowred[3][rl][1];
            float mean = s * (1.f / 256.f);
            float var = q * (1.f / 256.f) - mean * mean;
            float inv = 1.f / sqrtf(var + LEPS);
            size_t base = (size_t)(m0 + rl) * 256 + wc + (lane & 15);
#pragma unroll
            for (int nf = 0; nf < 4; nf++) {
                float o = (acc[mf][nf][r] - mean) * inv;
                outb[base + nf * 16] = (__bf16)o;
            }
        }
    }
}

// ---------------- pooling P1: per-(b,h) softmax -> normalized weights
__global__ __launch_bounds__(256) void pool_softmax(const float* __restrict__ pk,
                                                    const float* __restrict__ queries,
                                                    float* __restrict__ wout) {
    const int b = blockIdx.x, h = blockIdx.y;
    const int t = threadIdx.x;
    const int wv = t >> 6, lane = t & 63;
    __shared__ float qv[16];
    __shared__ float redm[4], reds[4];
    if (t < 16) qv[t] = queries[h * 16 + t];
    __syncthreads();
    float sc[4];
#pragma unroll
    for (int c = 0; c < 4; c++) {
        int s = c * 256 + t;
        const float* p = pk + ((size_t)b * SS + s) * 16;
        float4 a0 = *(const float4*)p;
        float4 a1 = *(const float4*)(p + 4);
        float4 a2 = *(const float4*)(p + 8);
        float4 a3 = *(const float4*)(p + 12);
        sc[c] = a0.x * qv[0] + a0.y * qv[1] + a0.z * qv[2] + a0.w * qv[3]
              + a1.x * qv[4] + a1.y * qv[5] + a1.z * qv[6] + a1.w * qv[7]
              + a2.x * qv[8] + a2.y * qv[9] + a2.z * qv[10] + a2.w * qv[11]
              + a3.x * qv[12] + a3.y * qv[13] + a3.z * qv[14] + a3.w * qv[15];
    }
    float m = fmaxf(fmaxf(sc[0], sc[1]), fmaxf(sc[2], sc[3]));
    for (int off = 32; off; off >>= 1) m = fmaxf(m, __shfl_xor(m, off, 64));
    if (lane == 0) redm[wv] = m;
    __syncthreads();
    m = fmaxf(fmaxf(redm[0], redm[1]), fmaxf(redm[2], redm[3]));
    float e[4];
    float sum = 0.f;
#pragma unroll
    for (int c = 0; c < 4; c++) { e[c] = expf(sc[c] - m); sum += e[c]; }
    for (int off = 32; off; off >>= 1) sum += __shfl_xor(sum, off, 64);
    if (lane == 0) reds[wv] = sum;
    __syncthreads();
    float inv = 1.f / (reds[0] + reds[1] + reds[2] + reds[3]);
#pragma unroll
    for (int c = 0; c < 4; c++)
        wout[((size_t)(b * 4 + h)) * SS + c * 256 + t] = e[c] * inv;
}

// ---------------- pooling P2: partial weighted sums over s-chunks of 64
__global__ __launch_bounds__(256) void pool_wsum(const float* __restrict__ wgt,
                                                 const float* __restrict__ pv,
                                                 float* __restrict__ partial) {
    const int b = blockIdx.x, c = blockIdx.y;
    const int h = threadIdx.x >> 6, d = threadIdx.x & 63;
    const float* wrow = wgt + ((size_t)(b * 4 + h)) * SS + c * 64;
    const float* pvb = pv + ((size_t)(b * SS + c * 64)) * 64 + d;
    float a = 0.f;
#pragma unroll 8
    for (int s = 0; s < 64; s++) a += wrow[s] * pvb[(size_t)s * 64];
    partial[((size_t)b * 16 + c) * 256 + threadIdx.x] = a;
}

// ---------------- pooling P3: reduce partials + final linear
__global__ __launch_bounds__(256) void pool_final(const float* __restrict__ partial,
                                                  const float* __restrict__ W1,
                                                  const float* __restrict__ b1,
                                                  float* __restrict__ out) {
    const int b = blockIdx.x, t = threadIdx.x;
    __shared__ float r0[256], r1[256];
    float a = 0.f;
#pragma unroll
    for (int c = 0; c < 16; c++) a += partial[((size_t)b * 16 + c) * 256 + t];
    r0[t] = a * W1[t * 2 + 0];
    r1[t] = a * W1[t * 2 + 1];
    __syncthreads();
    for (int off = 128; off > 0; off >>= 1) {
        if (t < off) { r0[t] += r0[t + off]; r1[t] += r1[t + off]; }
        __syncthreads();
    }
    if (t == 0) {
        out[b * 2 + 0] = r0[0] + b1[0];
        out[b * 2 + 1] = r1[0] + b1[1];
    }
}

extern "C" void kernel_launch(void* const* d_in, const int* in_sizes, int n_in,
                              void* d_out, int out_size, void* d_ws, size_t ws_size,
                              hipStream_t stream) {
    const float* input = (const float*)d_in[0];
    const float* eWk = (const float*)d_in[3];
    const float* ebk = (const float*)d_in[4];
    const float* eWq = (const float*)d_in[5];
    const float* ebq = (const float*)d_in[6];
    const float* eWv = (const float*)d_in[7];
    const float* ebv = (const float*)d_in[8];
    const float* eWb = (const float*)d_in[9];
    const float* ebb = (const float*)d_in[10];
    const float* eWff = (const float*)d_in[11];
    const float* ebff = (const float*)d_in[12];
    const float* eg1 = (const float*)d_in[13];
    const float* ebe1 = (const float*)d_in[14];
    const float* pWk = (const float*)d_in[15];
    const float* pbk = (const float*)d_in[16];
    const float* pWv = (const float*)d_in[17];
    const float* pbv = (const float*)d_in[18];
    const float* qrs = (const float*)d_in[19];
    const float* W1 = (const float*)d_in[20];
    const float* b1 = (const float*)d_in[21];
    float* out = (float*)d_out;

    // ---- workspace layout (bf16-only inter-kernel dataflow)
    float* ws = (float*)d_ws;
    float* xbuf = ws;                               // (reserved)
    __bf16* xbf = (__bf16*)(xbuf + (size_t)MM * DD);      // MM*256 bf16 — THE x
    float* tmp2 = (float*)(xbf + (size_t)MM * DD);        // tail scratch
    float* r3 = tmp2 + (size_t)MM * DD;
    __bf16* tmp2bf = (__bf16*)r3;                   //   LN1 bf16 (attn epilogue)
    __bf16* vTb = tmp2bf + (size_t)MM * DD;         //   vT [B][256][1024]
    float* r4 = r3 + (size_t)MM * DD;
    __bf16* kbf = (__bf16*)r4;                      //   k bf16
    __bf16* qbf = kbf + (size_t)MM * 64;            //   q bf16
    float* bbuf = r4 + (size_t)MM * (DD / 2);       // MM f32
    __bf16* wbf = (__bf16*)(bbuf + MM);             // weights bf16

    __bf16* WkqT = wbf;                     // [4][128][256]
    __bf16* WvT = WkqT + 4 * 128 * 256;     // [4][256][256]
    __bf16* WffT = WvT + 4 * 256 * 256;     // [4][256][256]
    __bf16* pWkT = WffT + 4 * 256 * 256;    // [16][256], pre-scaled
    __bf16* pWvT = pWkT + 16 * 256;         // [64][256]
    float* biasc = (float*)(pWvT + 64 * 256);  // [4][128]

    // tail-phase buffers inside tmp2 region
    float* pkbuf = tmp2;                        // MM*16
    float* pvbuf = tmp2 + (size_t)MM * 16;      // MM*64
    float* wgtbuf = tmp2 + (size_t)MM * 80;     // 32*4*1024
    float* partial = wgtbuf + (size_t)BB * 4 * SS;  // 32*16*256

    const float SC = 0.125f;  // 1/sqrt(64)

    cast_wt<<<dim3(64, 1, 4), 256, 0, stream>>>(eWk, WkqT, 64, SC, 128 * 256, 0);
    cast_wt<<<dim3(64, 1, 4), 256, 0, stream>>>(eWq, WkqT, 64, 1.f, 128 * 256, 64);
    cast_wt<<<dim3(256, 1, 4), 256, 0, stream>>>(eWv, WvT, 256, 1.f, 256 * 256, 0);
    cast_wt<<<dim3(256, 1, 4), 256, 0, stream>>>(eWff, WffT, 256, 1.f, 256 * 256, 0);
    cast_wt<<<dim3(16, 1, 1), 256, 0, stream>>>(pWk, pWkT, 16, SC, 16 * 256, 0);
    cast_wt<<<dim3(64, 1, 1), 256, 0, stream>>>(pWv, pWvT, 64, 1.f, 64 * 256, 0);
    bias_combine<<<4, 128, 0, stream>>>(ebk, ebq, biasc);
    cast_x<<<MM * DD / (256 * 8), 256, 0, stream>>>(input, xbf);

    for (int l = 0; l < 4; l++) {
        gemm_kq_vt<<<dim3(768, 1), 256, 0, stream>>>(
            xbf, WkqT + (size_t)l * 128 * 256, biasc + l * 128, kbf, qbf,
            WvT + (size_t)l * 256 * 256, ebv + l * DD, vTb,
            eWb + (size_t)l * DD, ebb + l, bbuf);
        attn_mfma<<<dim3(512, 1), 512, 0, stream>>>(kbf, qbf, vTb, bbuf, xbf,
                                                    eg1 + l * DD, ebe1 + l * DD, tmp2bf);
        gemm_ff_ln2<<<dim3(MM / 64, 1), 512, 0, stream>>>(
            tmp2bf, WffT + (size_t)l * 256 * 256, ebff + l * DD, tmp2bf, xbf);
    }
    gemm_mfma<16, 0><<<dim3(MM / 128, 1), 256, 0, stream>>>(xbf, pWkT, pbk, SC, 0, pkbuf, nullptr, 16);
    gemm_mfma<64, 0><<<dim3(MM / 128, 1), 256, 0, stream>>>(xbf, pWvT, pbv, 1.f, 0, pvbuf, nullptr, 64);
    pool_softmax<<<dim3(BB, 4), 256, 0, stream>>>(pkbuf, qrs, wgtbuf);
    pool_wsum<<<dim3(BB, 16), 256, 0, stream>>>(wgtbuf, pvbuf, partial);
    pool_final<<<BB, 256, 0, stream>>>(partial, W1, b1, out);
}

// Round 18
// 399.520 us; speedup vs baseline: 1.1279x; 1.0090x over previous
//
#include <hip/hip_runtime.h>
#include <hip/hip_bf16.h>
#include <math.h>

#define BB 32
#define SS 1024
#define DD 256
#define MM (BB*SS)   // 32768
#define LEPS 1e-5f

typedef __bf16 bf16x8 __attribute__((ext_vector_type(8)));
typedef __bf16 bf16x4 __attribute__((ext_vector_type(4)));
typedef float f32x4 __attribute__((ext_vector_type(4)));

// ---------------- scalar weight cast+transpose (small N only)
__global__ __launch_bounds__(256) void cast_wt(const float* __restrict__ W,
                                               __bf16* __restrict__ WT,
                                               int N, float scale, int dstride, int noff) {
    int n = blockIdx.x, l = blockIdx.z, k = threadIdx.x;
    WT[(size_t)dstride * l + (size_t)(n + noff) * 256 + k] =
        (__bf16)(W[(size_t)256 * N * l + (size_t)k * N + n] * scale);
}

// ---------------- tiled coalesced cast+transpose: WT[l][n+noff][k] = W[l][k][n]*scale
// 64x64 tiles via swizzled LDS (transpose_v pattern, fp32 in)
__global__ __launch_bounds__(256) void cast_wt_tiled(const float* __restrict__ W,
                                                     __bf16* __restrict__ WT,
                                                     int N, float scale, int dstride, int noff) {
    const int n0 = blockIdx.x * 64, k0 = blockIdx.y * 64, l = blockIdx.z;
    const int t = threadIdx.x;
    __shared__ __align__(16) __bf16 Ts[64][64];
    {
        int s = t >> 2, c0 = (t & 3) * 2;   // source row k0+s, 16 consecutive n
        const float* src = W + (size_t)256 * N * l + (size_t)(k0 + s) * N + n0 + c0 * 8;
        __bf16 tmp[16] __attribute__((aligned(16)));
#pragma unroll
        for (int u = 0; u < 16; u++) tmp[u] = (__bf16)(src[u] * scale);
        *(bf16x8*)&Ts[s][((c0 + 0) ^ (s & 7)) * 8] = *(bf16x8*)&tmp[0];
        *(bf16x8*)&Ts[s][((c0 + 1) ^ (s & 7)) * 8] = *(bf16x8*)&tmp[8];
    }
    __syncthreads();
    {
        int dr = t >> 2, sc = (t & 3) * 16;  // output row n0+dr, k chunk k0+sc
        __bf16 o[16] __attribute__((aligned(16)));
#pragma unroll
        for (int u = 0; u < 16; u++) {
            int row = sc + u;
            o[u] = Ts[row][((dr >> 3) ^ (row & 7)) * 8 + (dr & 7)];
        }
        __bf16* dst = WT + (size_t)dstride * l + (size_t)(n0 + noff + dr) * 256 + k0 + sc;
        *(bf16x8*)dst = *(bf16x8*)&o[0];
        *(bf16x8*)(dst + 8) = *(bf16x8*)&o[8];
    }
}

// ---------------- combined k/q bias: dst[l][j] = j<64 ? bk*SC : bq
__global__ __launch_bounds__(128) void bias_combine(const float* __restrict__ bk,
                                                    const float* __restrict__ bq,
                                                    float* __restrict__ dst) {
    int l = blockIdx.x, j = threadIdx.x;
    dst[l * 128 + j] = (j < 64) ? bk[l * 64 + j] * 0.125f : bq[l * 64 + (j - 64)];
}

// ---------------- cast fp32 -> bf16, 8 elems/thread
__global__ __launch_bounds__(256) void cast_x(const float* __restrict__ x, __bf16* __restrict__ xb) {
    size_t i = ((size_t)blockIdx.x * 256 + threadIdx.x) * 8;
    float4 a = *(const float4*)(x + i);
    float4 b = *(const float4*)(x + i + 4);
    __bf16 o[8] __attribute__((aligned(16)));
    o[0] = (__bf16)a.x; o[1] = (__bf16)a.y; o[2] = (__bf16)a.z; o[3] = (__bf16)a.w;
    o[4] = (__bf16)b.x; o[5] = (__bf16)b.y; o[6] = (__bf16)b.z; o[7] = (__bf16)b.w;
    *(bf16x8*)(xb + i) = *(bf16x8*)o;
}

// ---------------- fused per-layer kq-GEMM + bias-GEMV + vT-producer (768 blocks, 256 thr)
__global__ __launch_bounds__(256) void gemm_kq_vt(const __bf16* __restrict__ xbf,
                                                  const __bf16* __restrict__ WkqT,
                                                  const float* __restrict__ biasc,
                                                  __bf16* __restrict__ kq0,
                                                  __bf16* __restrict__ kq1,
                                                  const __bf16* __restrict__ WvT,
                                                  const float* __restrict__ bv,
                                                  __bf16* __restrict__ vTb,
                                                  const float* __restrict__ Wb,
                                                  const float* __restrict__ bb0,
                                                  float* __restrict__ bbuf_out) {
    const int t = threadIdx.x;
    const int w = t >> 6, lane = t & 63;
    const int wr = (w >> 1) * 64;
    const int wc = (w & 1) * 64;
    __shared__ __align__(16) __bf16 smem[128 * 64 + 128 * 64];
    __bf16 (*Al)[64] = (__bf16(*)[64])smem;
    __bf16 (*Wl)[64] = (__bf16(*)[64])(smem + 128 * 64);
    f32x4 acc[4][4] = {};

    const bool is_kq = (blockIdx.x < 256);
    const __bf16* A;
    const __bf16* WT;
    size_t wt_z = 0, c_z = 0;
    int m0, n0;
    if (is_kq) {
        A = xbf; WT = WkqT;
        m0 = blockIdx.x * 128; n0 = 0;
    } else {
        int v = blockIdx.x - 256;
        int bxv = v & 1, by = (v >> 1) & 7, bz = v >> 4;
        A = WvT; WT = xbf;
        m0 = bxv * 128; n0 = by * 128;
        wt_z = (size_t)bz * SS * 256;
        c_z = (size_t)bz * 256 * (size_t)SS;
    }

    float pb = 0.f;

    for (int k0 = 0; k0 < 256; k0 += 64) {
        __syncthreads();
        {
            int r = t >> 1, half = t & 1;
            const __bf16* src = A + (size_t)(m0 + r) * 256 + k0 + half * 32;
            bf16x8 v0 = *(const bf16x8*)(src);
            bf16x8 v1 = *(const bf16x8*)(src + 8);
            bf16x8 v2 = *(const bf16x8*)(src + 16);
            bf16x8 v3 = *(const bf16x8*)(src + 24);
            int cb = half * 4;
            *(bf16x8*)&Al[r][((cb + 0) ^ (r & 7)) * 8] = v0;
            *(bf16x8*)&Al[r][((cb + 1) ^ (r & 7)) * 8] = v1;
            *(bf16x8*)&Al[r][((cb + 2) ^ (r & 7)) * 8] = v2;
            *(bf16x8*)&Al[r][((cb + 3) ^ (r & 7)) * 8] = v3;
            if (is_kq) {
                const float* wbp = Wb + k0 + half * 32;
#pragma unroll
                for (int e = 0; e < 8; e++) {
                    pb += (float)v0[e] * wbp[e];
                    pb += (float)v1[e] * wbp[8 + e];
                    pb += (float)v2[e] * wbp[16 + e];
                    pb += (float)v3[e] * wbp[24 + e];
                }
            }
        }
        {
            int r = t >> 1, half = t & 1;
            const __bf16* src = WT + wt_z + (size_t)(n0 + r) * 256 + k0 + half * 32;
            bf16x8 v0 = *(const bf16x8*)(src);
            bf16x8 v1 = *(const bf16x8*)(src + 8);
            bf16x8 v2 = *(const bf16x8*)(src + 16);
            bf16x8 v3 = *(const bf16x8*)(src + 24);
            int cb = half * 4;
            *(bf16x8*)&Wl[r][((cb + 0) ^ (r & 7)) * 8] = v0;
            *(bf16x8*)&Wl[r][((cb + 1) ^ (r & 7)) * 8] = v1;
            *(bf16x8*)&Wl[r][((cb + 2) ^ (r & 7)) * 8] = v2;
            *(bf16x8*)&Wl[r][((cb + 3) ^ (r & 7)) * 8] = v3;
        }
        __syncthreads();
#pragma unroll
        for (int ks = 0; ks < 2; ks++) {
            int c = ks * 4 + (lane >> 4);
            bf16x8 af[4];
#pragma unroll
            for (int mf = 0; mf < 4; mf++) {
                int i = wr + mf * 16 + (lane & 15);
                af[mf] = *(const bf16x8*)&Al[i][(c ^ (i & 7)) * 8];
            }
#pragma unroll
            for (int nf = 0; nf < 4; nf++) {
                int n = wc + nf * 16 + (lane & 15);
                bf16x8 bfr = *(const bf16x8*)&Wl[n][(c ^ (n & 7)) * 8];
#pragma unroll
                for (int mf = 0; mf < 4; mf++)
                    acc[mf][nf] = __builtin_amdgcn_mfma_f32_16x16x32_bf16(af[mf], bfr, acc[mf][nf], 0, 0, 0);
            }
        }
    }
    if (is_kq) {
        float s = pb + __shfl_xor(pb, 1, 64);
        if ((t & 1) == 0) bbuf_out[m0 + (t >> 1)] = s + bb0[0];
#pragma unroll
        for (int mf = 0; mf < 4; mf++) {
#pragma unroll
            for (int nf = 0; nf < 4; nf++) {
                int col = wc + nf * 16 + (lane & 15);
                float bcol = biasc[col];
#pragma unroll
                for (int r = 0; r < 4; r++) {
                    int row = m0 + wr + mf * 16 + (lane >> 4) * 4 + r;
                    float v = acc[mf][nf][r] + bcol;
                    if (col < 64) kq0[(size_t)row * 64 + col] = (__bf16)v;
                    else kq1[(size_t)row * 64 + (col - 64)] = (__bf16)v;
                }
            }
        }
    } else {
        __syncthreads();
#pragma unroll
        for (int mf = 0; mf < 4; mf++) {
#pragma unroll
            for (int nf = 0; nf < 4; nf++) {
                int col = wc + nf * 16 + (lane & 15);
#pragma unroll
                for (int r = 0; r < 4; r++) {
                    int row = wr + mf * 16 + (lane >> 4) * 4 + r;
                    float v = acc[mf][nf][r] + bv[m0 + row];
                    smem[row * 128 + (((col >> 3) ^ (row & 15)) * 8) + (col & 7)] = (__bf16)v;
                }
            }
        }
        __syncthreads();
#pragma unroll
        for (int p = 0; p < 2; p++) {
            int row = p * 64 + (t >> 2);
            int cq = (t & 3) * 4;
            __bf16* dst = vTb + c_z + (size_t)(m0 + row) * SS + n0 + (t & 3) * 32;
#pragma unroll
            for (int u = 0; u < 4; u++) {
                int ch = (cq + u) ^ (row & 15);
                *(bf16x8*)(dst + u * 8) = *(const bf16x8*)&smem[row * 128 + ch * 8];
            }
        }
    }
}

// ---------------- MFMA GEMM (tail only): C = A[M,256] @ WT[N,256]^T + bias
template <int BN, int MODE>
__global__ __launch_bounds__(256) void gemm_mfma(const __bf16* __restrict__ A,
                                                 const __bf16* __restrict__ WT,
                                                 const float* __restrict__ bias,
                                                 float bscale, int relu,
                                                 void* __restrict__ Cv, void* __restrict__ Cv2,
                                                 int N) {
    constexpr int MR = (BN == 128) ? 4 : 2;
    constexpr int NC = (BN == 128) ? 4 : BN / 16;
    const int t = threadIdx.x;
    const int w = t >> 6, lane = t & 63;
    const int m0 = blockIdx.x * 128;
    const int n0 = blockIdx.y * BN;
    const int wr = (BN == 128) ? (w >> 1) * 64 : w * 32;
    const int wc = (BN == 128) ? (w & 1) * 64 : 0;
    __shared__ __align__(16) __bf16 smem[128 * 64 + BN * 64];
    __bf16 (*Al)[64] = (__bf16(*)[64])smem;
    __bf16 (*Wl)[64] = (__bf16(*)[64])(smem + 128 * 64);
    f32x4 acc[MR][NC] = {};

    for (int k0 = 0; k0 < 256; k0 += 64) {
        __syncthreads();
        {
            int r = t >> 1, half = t & 1;
            const __bf16* src = A + (size_t)(m0 + r) * 256 + k0 + half * 32;
            bf16x8 v0 = *(const bf16x8*)(src);
            bf16x8 v1 = *(const bf16x8*)(src + 8);
            bf16x8 v2 = *(const bf16x8*)(src + 16);
            bf16x8 v3 = *(const bf16x8*)(src + 24);
            int cb = half * 4;
            *(bf16x8*)&Al[r][((cb + 0) ^ (r & 7)) * 8] = v0;
            *(bf16x8*)&Al[r][((cb + 1) ^ (r & 7)) * 8] = v1;
            *(bf16x8*)&Al[r][((cb + 2) ^ (r & 7)) * 8] = v2;
            *(bf16x8*)&Al[r][((cb + 3) ^ (r & 7)) * 8] = v3;
        }
        if (BN == 64) {
            int n = t >> 2, q = t & 3;
            const __bf16* src = WT + (size_t)(n0 + n) * 256 + k0 + q * 16;
            bf16x8 v0 = *(const bf16x8*)src;
            bf16x8 v1 = *(const bf16x8*)(src + 8);
            *(bf16x8*)&Wl[n][((q * 2 + 0) ^ (n & 7)) * 8] = v0;
            *(bf16x8*)&Wl[n][((q * 2 + 1) ^ (n & 7)) * 8] = v1;
        } else {
            if (t < 128) {
                int n = t >> 3, c = t & 7;
                bf16x8 v = *(const bf16x8*)(WT + (size_t)(n0 + n) * 256 + k0 + c * 8);
                *(bf16x8*)&Wl[n][(c ^ (n & 7)) * 8] = v;
            }
        }
        __syncthreads();
#pragma unroll
        for (int ks = 0; ks < 2; ks++) {
            int c = ks * 4 + (lane >> 4);
            bf16x8 af[MR];
#pragma unroll
            for (int mf = 0; mf < MR; mf++) {
                int i = wr + mf * 16 + (lane & 15);
                af[mf] = *(const bf16x8*)&Al[i][(c ^ (i & 7)) * 8];
            }
#pragma unroll
            for (int nf = 0; nf < NC; nf++) {
                int n = wc + nf * 16 + (lane & 15);
                bf16x8 bfr = *(const bf16x8*)&Wl[n][(c ^ (n & 7)) * 8];
#pragma unroll
                for (int mf = 0; mf < MR; mf++)
                    acc[mf][nf] = __builtin_amdgcn_mfma_f32_16x16x32_bf16(af[mf], bfr, acc[mf][nf], 0, 0, 0);
            }
        }
    }
#pragma unroll
    for (int mf = 0; mf < MR; mf++) {
#pragma unroll
        for (int nf = 0; nf < NC; nf++) {
            int col = n0 + wc + nf * 16 + (lane & 15);
            float bcol = bias[col] * bscale;
#pragma unroll
            for (int r = 0; r < 4; r++) {
                int row = m0 + wr + mf * 16 + (lane >> 4) * 4 + r;
                float v = acc[mf][nf][r] + bcol;
                if (relu) v = fmaxf(v, 0.f);
                ((float*)Cv)[(size_t)row * N + col] = v;
            }
        }
    }
}

// ---------------- MFMA fused attention + LN1 (8 waves, j-tile 64, 16x16 MFMA)
// R13-proven version: Kl/bsh in LDS, T14 async-stage + setprio, bf16 dataflow.
__global__ __launch_bounds__(512, 4) void attn_mfma(const __bf16* __restrict__ kb,
                                                    const __bf16* __restrict__ qb,
                                                    const __bf16* __restrict__ vT,
                                                    const float* __restrict__ biasb,
                                                    const __bf16* __restrict__ xinb,
                                                    const float* __restrict__ gamma,
                                                    const float* __restrict__ beta,
                                                    __bf16* __restrict__ outb) {
    int h = blockIdx.x;
    int blow = h & 7, rest = h >> 3;
    int ib = rest & 15;
    int b = blow + (rest >> 4) * 8;
    const int i0 = ib * 64;
    const int t = threadIdx.x;
    const int w = t >> 6, lane = t & 63;
    const int iq = w >> 1;
    const int dhalf = w & 1;

    __shared__ __align__(16) __bf16 Kl[64][64];
    __shared__ __align__(16) __bf16 Ql[64][64];
    __shared__ __align__(16) __bf16 Vl[256][64];
    __shared__ __align__(16) __bf16 Sl[64][64];
    __shared__ float bsh[64];
    __shared__ float rowred[2][64][2];

    const int qj = t >> 3, qc = t & 7;
    const __bf16* qsrc_base = qb + ((size_t)(b * SS + qj)) * 64 + qc * 8;
    const int vd = t >> 1, vjh = t & 1;
    const __bf16* vsrc_base = vT + ((size_t)b * 256 + vd) * SS + vjh * 32;

    {   // stage K once + bias
        int i = t >> 3, c = t & 7;
        bf16x8 v = *(const bf16x8*)(kb + ((size_t)(b * SS + i0 + i)) * 64 + c * 8);
        *(bf16x8*)&Kl[i][(c ^ (i & 7)) * 8] = v;
        if (t < 64) bsh[t] = biasb[b * SS + i0 + t];
    }
    {   // prologue: stage Q/V for j0=0
        bf16x8 qv = *(const bf16x8*)(qsrc_base);
        *(bf16x8*)&Ql[qj][(qc ^ (qj & 7)) * 8] = qv;
#pragma unroll
        for (int u = 0; u < 4; u++) {
            bf16x8 v = *(const bf16x8*)(vsrc_base + u * 8);
            *(bf16x8*)&Vl[vd][((vjh * 4 + u) ^ (vd & 7)) * 8] = v;
        }
    }
    __syncthreads();

    f32x4 acc[8] = {};

    for (int j0 = 0; j0 < SS; j0 += 64) {
        const bool has_next = (j0 + 64) < SS;
        bf16x8 qn;
        bf16x8 vn0, vn1, vn2, vn3;
        if (has_next) {
            qn = *(const bf16x8*)(qsrc_base + (size_t)(j0 + 64) * 64);
            const __bf16* vs = vsrc_base + j0 + 64;
            vn0 = *(const bf16x8*)(vs);
            vn1 = *(const bf16x8*)(vs + 8);
            vn2 = *(const bf16x8*)(vs + 16);
            vn3 = *(const bf16x8*)(vs + 24);
        }
        // ---- S phase
#pragma unroll
        for (int jj = 0; jj < 2; jj++) {
            int jq = (w & 1) * 2 + jj;
            f32x4 sacc = {0.f, 0.f, 0.f, 0.f};
            __builtin_amdgcn_s_setprio(1);
#pragma unroll
            for (int ks = 0; ks < 2; ks++) {
                int i = iq * 16 + (lane & 15);
                int ck = ks * 4 + (lane >> 4);
                bf16x8 a = *(const bf16x8*)&Kl[i][(ck ^ (i & 7)) * 8];
                int j = jq * 16 + (lane & 15);
                bf16x8 bq = *(const bf16x8*)&Ql[j][(ck ^ (j & 7)) * 8];
                sacc = __builtin_amdgcn_mfma_f32_16x16x32_bf16(a, bq, sacc, 0, 0, 0);
            }
            __builtin_amdgcn_s_setprio(0);
            int jcol = jq * 16 + (lane & 15);
#pragma unroll
            for (int r = 0; r < 4; r++) {
                int irow = iq * 16 + (lane >> 4) * 4 + r;
                float x = sacc[r] + bsh[irow];
                float sg = 1.f / (1.f + __expf(-x));
                Sl[irow][(((jcol >> 3) ^ (irow & 7)) * 8) + (jcol & 7)] = (__bf16)sg;
            }
        }
        __syncthreads();
        // ---- PV phase
        bf16x8 am[2];
#pragma unroll
        for (int m = 0; m < 2; m++) {
            int i = iq * 16 + (lane & 15);
            int cj = m * 4 + (lane >> 4);
            am[m] = *(const bf16x8*)&Sl[i][(cj ^ (i & 7)) * 8];
        }
        __builtin_amdgcn_s_setprio(1);
#pragma unroll
        for (int dq = 0; dq < 8; dq++) {
            int d = dhalf * 128 + dq * 16 + (lane & 15);
#pragma unroll
            for (int m = 0; m < 2; m++) {
                int cj = m * 4 + (lane >> 4);
                bf16x8 bv = *(const bf16x8*)&Vl[d][(cj ^ (d & 7)) * 8];
                acc[dq] = __builtin_amdgcn_mfma_f32_16x16x32_bf16(am[m], bv, acc[dq], 0, 0, 0);
            }
        }
        __builtin_amdgcn_s_setprio(0);
        __syncthreads();
        if (has_next) {
            *(bf16x8*)&Ql[qj][(qc ^ (qj & 7)) * 8] = qn;
            *(bf16x8*)&Vl[vd][((vjh * 4 + 0) ^ (vd & 7)) * 8] = vn0;
            *(bf16x8*)&Vl[vd][((vjh * 4 + 1) ^ (vd & 7)) * 8] = vn1;
            *(bf16x8*)&Vl[vd][((vjh * 4 + 2) ^ (vd & 7)) * 8] = vn2;
            *(bf16x8*)&Vl[vd][((vjh * 4 + 3) ^ (vd & 7)) * 8] = vn3;
            __syncthreads();
        }
    }

    // ---- fused LN1 epilogue (bf16 residual)
#pragma unroll
    for (int r = 0; r < 4; r++) {
        int il = iq * 16 + (lane >> 4) * 4 + r;
        size_t rowoff = ((size_t)(b * SS + i0 + il)) * 256 + dhalf * 128 + (lane & 15);
#pragma unroll
        for (int dq = 0; dq < 8; dq++)
            acc[dq][r] += (float)xinb[rowoff + dq * 16];
    }
    float sr[4], qr[4];
#pragma unroll
    for (int r = 0; r < 4; r++) {
        float s = 0.f, q = 0.f;
#pragma unroll
        for (int dq = 0; dq < 8; dq++) {
            float v = acc[dq][r];
            s += v; q += v * v;
        }
#pragma unroll
        for (int mask = 8; mask; mask >>= 1) {
            s += __shfl_xor(s, mask, 64);
            q += __shfl_xor(q, mask, 64);
        }
        sr[r] = s; qr[r] = q;
    }
    if ((lane & 15) == 0) {
#pragma unroll
        for (int r = 0; r < 4; r++) {
            int il = iq * 16 + (lane >> 4) * 4 + r;
            rowred[dhalf][il][0] = sr[r];
            rowred[dhalf][il][1] = qr[r];
        }
    }
    __syncthreads();
    float gv[8], bv2[8];
#pragma unroll
    for (int dq = 0; dq < 8; dq++) {
        int d = dhalf * 128 + dq * 16 + (lane & 15);
        gv[dq] = gamma[d];
        bv2[dq] = beta[d];
    }
#pragma unroll
    for (int r = 0; r < 4; r++) {
        int il = iq * 16 + (lane >> 4) * 4 + r;
        float st = rowred[0][il][0] + rowred[1][il][0];
        float qt = rowred[0][il][1] + rowred[1][il][1];
        float mean = st * (1.f / 256.f);
        float var = qt * (1.f / 256.f) - mean * mean;
        float inv = 1.f / sqrtf(var + LEPS);
        size_t rowoff = ((size_t)(b * SS + i0 + il)) * 256 + dhalf * 128 + (lane & 15);
#pragma unroll
        for (int dq = 0; dq < 8; dq++) {
            float o = (acc[dq][r] - mean) * inv * gv[dq] + bv2[dq];
            outb[rowoff + dq * 16] = (__bf16)o;
        }
    }
}

// ---------------- ff GEMM (BM=64, BN=256, 8 waves, grid 512) + fused LN2 (no affine)
__global__ __launch_bounds__(512) void gemm_ff_ln2(const __bf16* __restrict__ A,
                                                   const __bf16* __restrict__ WT,
                                                   const float* __restrict__ bias,
                                                   const __bf16* __restrict__ resid,
                                                   __bf16* __restrict__ outb) {
    const int t = threadIdx.x;
    const int w = t >> 6, lane = t & 63;
    const int m0 = blockIdx.x * 64;
    const int wr = (w >> 2) * 32, wc = (w & 3) * 64;
    __shared__ __align__(16) __bf16 Al[64][64];
    __shared__ __align__(16) __bf16 Wl[256][64];
    __shared__ float rowred[4][64][2];
    f32x4 acc[2][4] = {};

    for (int k0 = 0; k0 < 256; k0 += 64) {
        __syncthreads();
        {
            int r = t >> 3, c = t & 7;
            bf16x8 v = *(const bf16x8*)(A + (size_t)(m0 + r) * 256 + k0 + c * 8);
            *(bf16x8*)&Al[r][(c ^ (r & 7)) * 8] = v;
        }
        {
            int n = t >> 1, c0 = (t & 1) * 4;
            const __bf16* src = WT + (size_t)n * 256 + k0 + c0 * 8;
#pragma unroll
            for (int u = 0; u < 4; u++) {
                bf16x8 v = *(const bf16x8*)(src + u * 8);
                *(bf16x8*)&Wl[n][((c0 + u) ^ (n & 7)) * 8] = v;
            }
        }
        __syncthreads();
#pragma unroll
        for (int ks = 0; ks < 2; ks++) {
            int c = ks * 4 + (lane >> 4);
            bf16x8 af[2];
#pragma unroll
            for (int mf = 0; mf < 2; mf++) {
                int i = wr + mf * 16 + (lane & 15);
                af[mf] = *(const bf16x8*)&Al[i][(c ^ (i & 7)) * 8];
            }
#pragma unroll
            for (int nf = 0; nf < 4; nf++) {
                int n = wc + nf * 16 + (lane & 15);
                bf16x8 bfr = *(const bf16x8*)&Wl[n][(c ^ (n & 7)) * 8];
#pragma unroll
                for (int mf = 0; mf < 2; mf++)
                    acc[mf][nf] = __builtin_amdgcn_mfma_f32_16x16x32_bf16(af[mf], bfr, acc[mf][nf], 0, 0, 0);
            }
        }
    }
    float colb[4];
#pragma unroll
    for (int nf = 0; nf < 4; nf++) colb[nf] = bias[wc + nf * 16 + (lane & 15)];
#pragma unroll
    for (int mf = 0; mf < 2; mf++) {
#pragma unroll
        for (int r = 0; r < 4; r++) {
            int rl = wr + mf * 16 + (lane >> 4) * 4 + r;
            const __bf16* rrow = resid + (size_t)(m0 + rl) * 256 + wc + (lane & 15);
            float s = 0.f, q = 0.f;
#pragma unroll
            for (int nf = 0; nf < 4; nf++) {
                float v = fmaxf(acc[mf][nf][r] + colb[nf], 0.f) + (float)rrow[nf * 16];
                acc[mf][nf][r] = v;
                s += v; q += v * v;
            }
#pragma unroll
            for (int msk = 1; msk <= 8; msk <<= 1) {
                s += __shfl_xor(s, msk, 64);
                q += __shfl_xor(q, msk, 64);
            }
            if ((lane & 15) == 0) {
                rowred[w & 3][rl][0] = s;
                rowred[w & 3][rl][1] = q;
            }
        }
    }
    __syncthreads();
#pragma unroll
    for (int mf = 0; mf < 2; mf++) {
#pragma unroll
        for (int r = 0; r < 4; r++) {
            int rl = wr + mf * 16 + (lane >> 4) * 4 + r;
            float s = rowred[0][rl][0] + rowred[1][rl][0] + rowred[2][rl][0] + rowred[3][rl][0];
            float q = rowred[0][rl][1] + rowred[1][rl][1] + rowred[2][rl][1] + rowred[3][rl][1];
            float mean = s * (1.f / 256.f);
            float var = q * (1.f / 256.f) - mean * mean;
            float inv = 1.f / sqrtf(var + LEPS);
            size_t base = (size_t)(m0 + rl) * 256 + wc + (lane & 15);
#pragma unroll
            for (int nf = 0; nf < 4; nf++) {
                float o = (acc[mf][nf][r] - mean) * inv;
                outb[base + nf * 16] = (__bf16)o;
            }
        }
    }
}

// ---------------- pooling P1: per-(b,h) softmax -> normalized weights
__global__ __launch_bounds__(256) void pool_softmax(const float* __restrict__ pk,
                                                    const float* __restrict__ queries,
                                                    float* __restrict__ wout) {
    const int b = blockIdx.x, h = blockIdx.y;
    const int t = threadIdx.x;
    const int wv = t >> 6, lane = t & 63;
    __shared__ float qv[16];
    __shared__ float redm[4], reds[4];
    if (t < 16) qv[t] = queries[h * 16 + t];
    __syncthreads();
    float sc[4];
#pragma unroll
    for (int c = 0; c < 4; c++) {
        int s = c * 256 + t;
        const float* p = pk + ((size_t)b * SS + s) * 16;
        float4 a0 = *(const float4*)p;
        float4 a1 = *(const float4*)(p + 4);
        float4 a2 = *(const float4*)(p + 8);
        float4 a3 = *(const float4*)(p + 12);
        sc[c] = a0.x * qv[0] + a0.y * qv[1] + a0.z * qv[2] + a0.w * qv[3]
              + a1.x * qv[4] + a1.y * qv[5] + a1.z * qv[6] + a1.w * qv[7]
              + a2.x * qv[8] + a2.y * qv[9] + a2.z * qv[10] + a2.w * qv[11]
              + a3.x * qv[12] + a3.y * qv[13] + a3.z * qv[14] + a3.w * qv[15];
    }
    float m = fmaxf(fmaxf(sc[0], sc[1]), fmaxf(sc[2], sc[3]));
    for (int off = 32; off; off >>= 1) m = fmaxf(m, __shfl_xor(m, off, 64));
    if (lane == 0) redm[wv] = m;
    __syncthreads();
    m = fmaxf(fmaxf(redm[0], redm[1]), fmaxf(redm[2], redm[3]));
    float e[4];
    float sum = 0.f;
#pragma unroll
    for (int c = 0; c < 4; c++) { e[c] = expf(sc[c] - m); sum += e[c]; }
    for (int off = 32; off; off >>= 1) sum += __shfl_xor(sum, off, 64);
    if (lane == 0) reds[wv] = sum;
    __syncthreads();
    float inv = 1.f / (reds[0] + reds[1] + reds[2] + reds[3]);
#pragma unroll
    for (int c = 0; c < 4; c++)
        wout[((size_t)(b * 4 + h)) * SS + c * 256 + t] = e[c] * inv;
}

// ---------------- pooling P2: partial weighted sums over s-chunks of 64
__global__ __launch_bounds__(256) void pool_wsum(const float* __restrict__ wgt,
                                                 const float* __restrict__ pv,
                                                 float* __restrict__ partial) {
    const int b = blockIdx.x, c = blockIdx.y;
    const int h = threadIdx.x >> 6, d = threadIdx.x & 63;
    const float* wrow = wgt + ((size_t)(b * 4 + h)) * SS + c * 64;
    const float* pvb = pv + ((size_t)(b * SS + c * 64)) * 64 + d;
    float a = 0.f;
#pragma unroll 8
    for (int s = 0; s < 64; s++) a += wrow[s] * pvb[(size_t)s * 64];
    partial[((size_t)b * 16 + c) * 256 + threadIdx.x] = a;
}

// ---------------- pooling P3: reduce partials + final linear
__global__ __launch_bounds__(256) void pool_final(const float* __restrict__ partial,
                                                  const float* __restrict__ W1,
                                                  const float* __restrict__ b1,
                                                  float* __restrict__ out) {
    const int b = blockIdx.x, t = threadIdx.x;
    __shared__ float r0[256], r1[256];
    float a = 0.f;
#pragma unroll
    for (int c = 0; c < 16; c++) a += partial[((size_t)b * 16 + c) * 256 + t];
    r0[t] = a * W1[t * 2 + 0];
    r1[t] = a * W1[t * 2 + 1];
    __syncthreads();
    for (int off = 128; off > 0; off >>= 1) {
        if (t < off) { r0[t] += r0[t + off]; r1[t] += r1[t + off]; }
        __syncthreads();
    }
    if (t == 0) {
        out[b * 2 + 0] = r0[0] + b1[0];
        out[b * 2 + 1] = r1[0] + b1[1];
    }
}

extern "C" void kernel_launch(void* const* d_in, const int* in_sizes, int n_in,
                              void* d_out, int out_size, void* d_ws, size_t ws_size,
                              hipStream_t stream) {
    const float* input = (const float*)d_in[0];
    const float* eWk = (const float*)d_in[3];
    const float* ebk = (const float*)d_in[4];
    const float* eWq = (const float*)d_in[5];
    const float* ebq = (const float*)d_in[6];
    const float* eWv = (const float*)d_in[7];
    const float* ebv = (const float*)d_in[8];
    const float* eWb = (const float*)d_in[9];
    const float* ebb = (const float*)d_in[10];
    const float* eWff = (const float*)d_in[11];
    const float* ebff = (const float*)d_in[12];
    const float* eg1 = (const float*)d_in[13];
    const float* ebe1 = (const float*)d_in[14];
    const float* pWk = (const float*)d_in[15];
    const float* pbk = (const float*)d_in[16];
    const float* pWv = (const float*)d_in[17];
    const float* pbv = (const float*)d_in[18];
    const float* qrs = (const float*)d_in[19];
    const float* W1 = (const float*)d_in[20];
    const float* b1 = (const float*)d_in[21];
    float* out = (float*)d_out;

    // ---- workspace layout (bf16-only inter-kernel dataflow)
    float* ws = (float*)d_ws;
    float* xbuf = ws;                               // (reserved)
    __bf16* xbf = (__bf16*)(xbuf + (size_t)MM * DD);      // MM*256 bf16 — THE x
    float* tmp2 = (float*)(xbf + (size_t)MM * DD);        // tail scratch
    float* r3 = tmp2 + (size_t)MM * DD;
    __bf16* tmp2bf = (__bf16*)r3;                   //   LN1 bf16 (attn epilogue)
    __bf16* vTb = tmp2bf + (size_t)MM * DD;         //   vT [B][256][1024]
    float* r4 = r3 + (size_t)MM * DD;
    __bf16* kbf = (__bf16*)r4;                      //   k bf16
    __bf16* qbf = kbf + (size_t)MM * 64;            //   q bf16
    float* bbuf = r4 + (size_t)MM * (DD / 2);       // MM f32
    __bf16* wbf = (__bf16*)(bbuf + MM);             // weights bf16

    __bf16* WkqT = wbf;                     // [4][128][256]
    __bf16* WvT = WkqT + 4 * 128 * 256;     // [4][256][256]
    __bf16* WffT = WvT + 4 * 256 * 256;     // [4][256][256]
    __bf16* pWkT = WffT + 4 * 256 * 256;    // [16][256], pre-scaled
    __bf16* pWvT = pWkT + 16 * 256;         // [64][256]
    float* biasc = (float*)(pWvT + 64 * 256);  // [4][128]

    // tail-phase buffers inside tmp2 region
    float* pkbuf = tmp2;                        // MM*16
    float* pvbuf = tmp2 + (size_t)MM * 16;      // MM*64
    float* wgtbuf = tmp2 + (size_t)MM * 80;     // 32*4*1024
    float* partial = wgtbuf + (size_t)BB * 4 * SS;  // 32*16*256

    const float SC = 0.125f;  // 1/sqrt(64)

    cast_wt_tiled<<<dim3(1, 4, 4), 256, 0, stream>>>(eWk, WkqT, 64, SC, 128 * 256, 0);
    cast_wt_tiled<<<dim3(1, 4, 4), 256, 0, stream>>>(eWq, WkqT, 64, 1.f, 128 * 256, 64);
    cast_wt_tiled<<<dim3(4, 4, 4), 256, 0, stream>>>(eWv, WvT, 256, 1.f, 256 * 256, 0);
    cast_wt_tiled<<<dim3(4, 4, 4), 256, 0, stream>>>(eWff, WffT, 256, 1.f, 256 * 256, 0);
    cast_wt<<<dim3(16, 1, 1), 256, 0, stream>>>(pWk, pWkT, 16, SC, 16 * 256, 0);
    cast_wt_tiled<<<dim3(1, 4, 1), 256, 0, stream>>>(pWv, pWvT, 64, 1.f, 64 * 256, 0);
    bias_combine<<<4, 128, 0, stream>>>(ebk, ebq, biasc);
    cast_x<<<MM * DD / (256 * 8), 256, 0, stream>>>(input, xbf);

    for (int l = 0; l < 4; l++) {
        gemm_kq_vt<<<dim3(768, 1), 256, 0, stream>>>(
            xbf, WkqT + (size_t)l * 128 * 256, biasc + l * 128, kbf, qbf,
            WvT + (size_t)l * 256 * 256, ebv + l * DD, vTb,
            eWb + (size_t)l * DD, ebb + l, bbuf);
        attn_mfma<<<dim3(512, 1), 512, 0, stream>>>(kbf, qbf, vTb, bbuf, xbf,
                                                    eg1 + l * DD, ebe1 + l * DD, tmp2bf);
        gemm_ff_ln2<<<dim3(MM / 64, 1), 512, 0, stream>>>(
            tmp2bf, WffT + (size_t)l * 256 * 256, ebff + l * DD, tmp2bf, xbf);
    }
    gemm_mfma<16, 0><<<dim3(MM / 128, 1), 256, 0, stream>>>(xbf, pWkT, pbk, SC, 0, pkbuf, nullptr, 16);
    gemm_mfma<64, 0><<<dim3(MM / 128, 1), 256, 0, stream>>>(xbf, pWvT, pbv, 1.f, 0, pvbuf, nullptr, 64);
    pool_softmax<<<dim3(BB, 4), 256, 0, stream>>>(pkbuf, qrs, wgtbuf);
    pool_wsum<<<dim3(BB, 16), 256, 0, stream>>>(wgtbuf, pvbuf, partial);
    pool_final<<<BB, 256, 0, stream>>>(partial, W1, b1, out);
}